// Round 11
// baseline (265.641 us; speedup 1.0000x reference)
//
#include <hip/hip_runtime.h>
#include <stdint.h>

typedef unsigned short u16;
typedef unsigned int u32;
typedef __bf16 bf16x8 __attribute__((ext_vector_type(8)));
typedef float f32x4 __attribute__((ext_vector_type(4)));
typedef unsigned short u16x8 __attribute__((ext_vector_type(8)));
typedef unsigned short u16x4 __attribute__((ext_vector_type(4)));
typedef u16x8 u16x8_a __attribute__((may_alias));
typedef u16x4 u16x4_a __attribute__((may_alias));

#define DEV static __device__ __forceinline__

DEV u16 f2bf(float f) {
  unsigned u = __builtin_bit_cast(unsigned, f);
  u += 0x7fffu + ((u >> 16) & 1u);   // RNE
  return (u16)(u >> 16);
}
DEV bf16x8 ld8(const u16* p) {
  u16x8 v = *(const u16x8_a*)p;
  return __builtin_bit_cast(bf16x8, v);
}
DEV f32x4 vmax4(f32x4 a, f32x4 b) {
  f32x4 r;
  r[0] = fmaxf(a[0], b[0]); r[1] = fmaxf(a[1], b[1]);
  r[2] = fmaxf(a[2], b[2]); r[3] = fmaxf(a[3], b[3]);
  return r;
}
// bijective XCD swizzle (m204)
DEV void swz_block(int& bx, int& by) {
  const int gx = gridDim.x;
  const int nwg = gx * gridDim.y;
  int lin = by * gx + bx;
  const int q = nwg >> 3, r = nwg & 7, x = lin & 7, p = lin >> 3;
  lin = (x < r ? x * (q + 1) : r * (q + 1) + (x - r) * q) + p;
  bx = lin % gx; by = lin / gx;
}

#define GL_LDS16(gp, lp)                                                        \
  __builtin_amdgcn_global_load_lds(                                             \
      (const __attribute__((address_space(1))) void*)(gp),                      \
      (__attribute__((address_space(3))) void*)(lp), 16, 0, 0)

#define VMW12 asm volatile("s_waitcnt vmcnt(12)" ::: "memory")
#define VMW8  asm volatile("s_waitcnt vmcnt(8)" ::: "memory")
#define VMW6  asm volatile("s_waitcnt vmcnt(6)" ::: "memory")
#define VMW4  asm volatile("s_waitcnt vmcnt(4)" ::: "memory")
#define VMW2  asm volatile("s_waitcnt vmcnt(2)" ::: "memory")
#define VMW0  asm volatile("s_waitcnt vmcnt(0)" ::: "memory")
#define BAR   __builtin_amdgcn_s_barrier()

// ---------------- f32 -> bf16 convert ----------------
__global__ __launch_bounds__(256) void cvt_k(const float* __restrict__ s,
                                             u16* __restrict__ d, int n4) {
  int i = blockIdx.x * 256 + threadIdx.x;
  if (i < n4) {
    float4 v = ((const float4*)s)[i];
    u16x4 o;
    o[0] = f2bf(v.x); o[1] = f2bf(v.y); o[2] = f2bf(v.z); o[3] = f2bf(v.w);
    *(u16x4_a*)(d + (size_t)i * 4) = o;
  }
}

// ---------------- layernorm (f32 in, bf16 out) ----------------
__global__ __launch_bounds__(256) void ln_k(const float* __restrict__ x,
                                            const float* __restrict__ w,
                                            const float* __restrict__ b,
                                            u16* __restrict__ o) {
  const int row = blockIdx.x, t = threadIdx.x;
  const float4 v = ((const float4*)(x + (size_t)row * 1024))[t];
  float s = v.x + v.y + v.z + v.w;
  float q = v.x * v.x + v.y * v.y + v.z * v.z + v.w * v.w;
#pragma unroll
  for (int m = 1; m < 64; m <<= 1) { s += __shfl_xor(s, m); q += __shfl_xor(q, m); }
  __shared__ float ss[4], qq[4];
  if ((t & 63) == 0) { ss[t >> 6] = s; qq[t >> 6] = q; }
  __syncthreads();
  s = ss[0] + ss[1] + ss[2] + ss[3];
  q = qq[0] + qq[1] + qq[2] + qq[3];
  const float mean = s * (1.f / 1024.f);
  const float var = q * (1.f / 1024.f) - mean * mean;
  const float rstd = rsqrtf(var + 1e-5f);
  const float4 wv = ((const float4*)w)[t];
  const float4 bv = ((const float4*)b)[t];
  u16x4 ov;
  ov[0] = f2bf((v.x - mean) * rstd * wv.x + bv.x);
  ov[1] = f2bf((v.y - mean) * rstd * wv.y + bv.y);
  ov[2] = f2bf((v.z - mean) * rstd * wv.z + bv.z);
  ov[3] = f2bf((v.w - mean) * rstd * wv.w + bv.w);
  *(u16x4_a*)(o + (size_t)row * 1024 + t * 4) = ov;
}

// ---------------- V transpose ----------------
__global__ __launch_bounds__(256) void vtr_k(const u16* __restrict__ qkvV,
                                             u16* __restrict__ vt) {
  __shared__ u16 T[64][65];
  const int st = blockIdx.x, bh = blockIdx.y;
  const int b = bh >> 4, h = bh & 15;
  const int t = threadIdx.x;
  const u16* src = qkvV + ((size_t)(b * 2048 + st * 64)) * 3072 + h * 64;
  const int r = t >> 2, c0 = (t & 3) * 16;
  u16x8 a0 = *(const u16x8_a*)(src + (size_t)r * 3072 + c0);
  u16x8 a1 = *(const u16x8_a*)(src + (size_t)r * 3072 + c0 + 8);
#pragma unroll
  for (int e = 0; e < 8; ++e) { T[r][c0 + e] = a0[e]; T[r][c0 + 8 + e] = a1[e]; }
  __syncthreads();
  const int d = t >> 2, s0 = (t & 3) * 16;
  u16x8 o0, o1;
#pragma unroll
  for (int e = 0; e < 8; ++e) { o0[e] = T[s0 + e][d]; o1[e] = T[s0 + 8 + e][d]; }
  u16* dst = vt + ((size_t)bh * 64 + d) * 2048 + (size_t)st * 64 + s0;
  *(u16x8_a*)dst = o0;
  *(u16x8_a*)(dst + 8) = o1;
}

// ================= 256x256 8-phase GEMM, rolling counted-vmcnt schedule =================
DEV void stage_op(const u16* __restrict__ G, int K, int kk, u16* lds, int set,
                  int isB, int w, int l) {
#pragma unroll
  for (int i = 0; i < 2; ++i) {
    const int c = i * 8 + w;                 // chunk 0..15 (1KB, 8 rows)
    int rb;
    if (!isB) { const int lr = c * 8; rb = (lr < 64 ? lr : lr + 64) + set * 64; }
    else      { rb = (c >> 2) * 64 + set * 32 + (c & 3) * 8; }
    const int row = rb + (l >> 3);
    const int c8 = (l & 7) ^ (row & 7);      // inverse-swizzled source col
    GL_LDS16(G + (size_t)row * K + kk + c8 * 8, lds + rb * 64);
  }
}
DEV void rdA(const u16* as, int wr, int mh, int l15, int l4, bf16x8 af[4][2]) {
#pragma unroll
  for (int f = 0; f < 4; ++f) {
    const int row = wr * 128 + mh * 64 + f * 16 + l15;
#pragma unroll
    for (int ks = 0; ks < 2; ++ks) {
      const int c8 = (ks * 4 + l4) ^ (row & 7);
      af[f][ks] = ld8(as + row * 64 + c8 * 8);
    }
  }
}
DEV void rdB(const u16* bs, int wc, int nh, int l15, int l4, bf16x8 bf_[2][2]) {
#pragma unroll
  for (int g = 0; g < 2; ++g) {
    const int row = wc * 64 + nh * 32 + g * 16 + l15;
#pragma unroll
    for (int ks = 0; ks < 2; ++ks) {
      const int c8 = (ks * 4 + l4) ^ (row & 7);
      bf_[g][ks] = ld8(bs + row * 64 + c8 * 8);
    }
  }
}

#define MFMA16(mh, nh)                                                          \
  __builtin_amdgcn_s_setprio(1);                                                \
  _Pragma("unroll")                                                             \
  for (int f = 0; f < 4; ++f) {                                                 \
    _Pragma("unroll")                                                           \
    for (int g = 0; g < 2; ++g) {                                               \
      f32x4& a_ = acc[(mh) * 4 + f][(nh) * 2 + g];                              \
      a_ = __builtin_amdgcn_mfma_f32_16x16x32_bf16(af[f][0], bfr[g][0], a_, 0, 0, 0); \
      a_ = __builtin_amdgcn_mfma_f32_16x16x32_bf16(af[f][1], bfr[g][1], a_, 0, 0, 0); \
    }                                                                           \
  }                                                                             \
  __builtin_amdgcn_s_setprio(0);

template <int EPI>
__global__ __launch_bounds__(512, 2) void gemm8(const u16* __restrict__ A,
                                                const u16* __restrict__ Bw,
                                                u16* __restrict__ Cp,
                                                int M, int N, int K, int qcols) {
  __shared__ __align__(16) u16 As[2][256 * 64];
  __shared__ __align__(16) u16 Bs[2][256 * 64];
  const int t = threadIdx.x, w = t >> 6, l = t & 63;
  const int l15 = l & 15, l4 = l >> 4;
  const int wr = w >> 2, wc = w & 3;
  int bx = blockIdx.x, by = blockIdx.y;
  swz_block(bx, by);
  const int bm0 = by * 256, bn0 = bx * 256;
  const u16* Ab = A + (size_t)bm0 * K;
  const u16* Bb = Bw + (size_t)bn0 * K;

  f32x4 acc[8][4] = {};
  stage_op(Ab, K, 0, As[0], 0, 0, w, l);
  stage_op(Bb, K, 0, Bs[0], 0, 1, w, l);
  stage_op(Bb, K, 0, Bs[0], 1, 1, w, l);
  stage_op(Ab, K, 0, As[0], 1, 0, w, l);
  VMW4;                                    // hA0,hB0 resident; {hB1,hA1} in flight
  BAR;

  const int nk = K >> 6;
  int cur = 0;
  bf16x8 af[4][2], bfr[2][2];
  for (int kt = 0; kt < nk; ++kt) {
    const int kn = (kt + 1) << 6;
    const bool more = (kt + 1 < nk);
    u16* An = As[cur ^ 1];
    u16* Bn = Bs[cur ^ 1];
    // ---- phase A: quad(0,0); prefetch hA0(t+1) ----
    rdA(As[cur], wr, 0, l15, l4, af);
    rdB(Bs[cur], wc, 0, l15, l4, bfr);
    if (more) stage_op(Ab, K, kn, An, 0, 0, w, l);
    BAR;
    MFMA16(0, 0)
    if (more) { VMW4; } else { VMW2; }     // drain hB1(kt) for phase B
    BAR;
    // ---- phase B: quad(0,1); prefetch hB0(t+1) ----
    rdB(Bs[cur], wc, 1, l15, l4, bfr);
    if (more) stage_op(Bb, K, kn, Bn, 0, 1, w, l);
    BAR;
    MFMA16(0, 1)
    if (more) { VMW4; } else { VMW0; }     // drain hA1(kt) for phase C
    BAR;
    // ---- phase C: quad(1,1); prefetch hB1(t+1) ----
    rdA(As[cur], wr, 1, l15, l4, af);
    if (more) stage_op(Bb, K, kn, Bn, 1, 1, w, l);
    BAR;
    MFMA16(1, 1)
    BAR;
    // ---- phase D: quad(1,0); prefetch hA1(t+1) ----
    rdB(Bs[cur], wc, 0, l15, l4, bfr);
    if (more) stage_op(Ab, K, kn, An, 1, 0, w, l);
    BAR;
    MFMA16(1, 0)
    if (more) { VMW4; }                    // hA0,hB0(t+1) landed
    BAR;
    cur ^= 1;
  }

#pragma unroll
  for (int m = 0; m < 8; ++m) {
    const int row0 = bm0 + wr * 128 + m * 16 + l4 * 4;
#pragma unroll
    for (int n = 0; n < 4; ++n) {
      const int col = bn0 + wc * 64 + n * 16 + l15;
      const float qs = (col < qcols) ? 0.125f : 1.f;
#pragma unroll
      for (int r = 0; r < 4; ++r) {
        float v = acc[m][n][r] * qs;
        if constexpr (EPI == 1) v = v > 0.f ? v : 0.f;
        Cp[(size_t)(row0 + r) * N + col] = f2bf(v);
      }
    }
  }
}

// ====== 128x128 deep-pipeline GEMM v2: A in LDS (3-buf), B global->reg (3 named bufs) ======
// 512 thr = 8 waves (2Mx4N, wave 64x32); per step: issue {stgA:2, ldB:4}; vmcnt(12) steady.
__global__ __launch_bounds__(512, 1) void gemm128(const u16* __restrict__ A,
                                                  const u16* __restrict__ Bw,
                                                  float* __restrict__ C,
                                                  const float* __restrict__ res,
                                                  int M, int N, int K) {
  __shared__ __align__(16) u16 As[3][128 * 64];
  const int t = threadIdx.x, w = t >> 6, l = t & 63;
  const int l15 = l & 15, l4 = l >> 4;
  const int wr = w >> 2, wc = w & 3;              // 2M x 4N
  int bx = blockIdx.x, by = blockIdx.y;
  swz_block(bx, by);
  const int bm0 = by * 128, bn0 = bx * 128;
  const u16* Ab = A + (size_t)bm0 * K;
  const u16* Bb = Bw + (size_t)bn0 * K;

  auto stgA = [&](int buf, int kk) {
#pragma unroll
    for (int i = 0; i < 2; ++i) {
      const int c = i * 8 + w;                    // 16 chunks x 8 rows
      const int row = c * 8 + (l >> 3);
      const int c8 = (l & 7) ^ (row & 7);
      GL_LDS16(Ab + (size_t)row * K + kk + c8 * 8, &As[buf][c * 512]);
    }
  };
  auto ldB = [&](bf16x8 (&bf_)[2][2], int kk) {   // global->reg, lanes cover full 64B lines
#pragma unroll
    for (int g = 0; g < 2; ++g) {
      const int row = wc * 32 + g * 16 + l15;
#pragma unroll
      for (int ks = 0; ks < 2; ++ks)
        bf_[g][ks] = ld8(Bb + (size_t)row * K + kk + (ks * 4 + l4) * 8);
    }
  };
  auto rdAf = [&](bf16x8 (&af)[4][2], int cb) {
#pragma unroll
    for (int f = 0; f < 4; ++f) {
      const int row = wr * 64 + f * 16 + l15;
#pragma unroll
      for (int ks = 0; ks < 2; ++ks)
        af[f][ks] = ld8(&As[cb][row * 64 + (((ks * 4 + l4) ^ (row & 7)) * 8)]);
    }
  };

  f32x4 acc[4][2] = {};
  bf16x8 b0[2][2], b1[2][2], b2[2][2];
  const int nk = K >> 6;
  // prologue: tiles 0,1 -> {A-LDS, B-regs}; 12 vm-ops outstanding
  stgA(0, 0);  ldB(b0, 0);
  stgA(1, 64); ldB(b1, 64);

#define G128_STEP(kt_, BUSE, BLOAD)                                            \
  {                                                                            \
    const int kt = (kt_);                                                      \
    if (kt >= nk) break;                                                       \
    if (kt + 2 < nk) { stgA((kt + 2) % 3, (kt + 2) << 6); ldB(BLOAD, (kt + 2) << 6); } \
    if (kt + 2 < nk) { VMW12; } else if (kt + 1 < nk) { VMW6; } else { VMW0; } \
    BAR;                                                                       \
    bf16x8 af[4][2];                                                           \
    rdAf(af, kt % 3);                                                          \
    __builtin_amdgcn_s_setprio(1);                                             \
    _Pragma("unroll")                                                          \
    for (int f = 0; f < 4; ++f) {                                              \
      _Pragma("unroll")                                                        \
      for (int g = 0; g < 2; ++g) {                                            \
        acc[f][g] = __builtin_amdgcn_mfma_f32_16x16x32_bf16(af[f][0], BUSE[g][0], acc[f][g], 0, 0, 0); \
        acc[f][g] = __builtin_amdgcn_mfma_f32_16x16x32_bf16(af[f][1], BUSE[g][1], acc[f][g], 0, 0, 0); \
      }                                                                        \
    }                                                                          \
    __builtin_amdgcn_s_setprio(0);                                             \
    BAR;                                                                       \
  }

  for (int ktb = 0;; ktb += 3) {
    G128_STEP(ktb + 0, b0, b2)
    G128_STEP(ktb + 1, b1, b0)
    G128_STEP(ktb + 2, b2, b1)
  }
#undef G128_STEP

#pragma unroll
  for (int f = 0; f < 4; ++f) {
    const int row0 = bm0 + wr * 64 + f * 16 + l4 * 4;
#pragma unroll
    for (int g = 0; g < 2; ++g) {
      const int col = bn0 + wc * 32 + g * 16 + l15;
#pragma unroll
      for (int r = 0; r < 4; ++r) {
        const size_t idx = (size_t)(row0 + r) * N + col;
        C[idx] = res[idx] + acc[f][g][r];
      }
    }
  }
}

// ---------------- causal flash attention v5: swapped QK^T, in-register softmax ----------
__global__ __launch_bounds__(256) void attn_k(const u16* __restrict__ Qm,
                                              const u16* __restrict__ Km,
                                              const u16* __restrict__ vt,
                                              u16* __restrict__ Om) {
  const int S = 2048, D = 1024, ldq = 3072;
  int p = blockIdx.x, bh = blockIdx.y;
  swz_block(p, bh);                          // same-bh pairs grouped per XCD
  const int bb = bh >> 4, h = bh & 15;
  const int t = threadIdx.x, w = t >> 6, l = t & 63, l15 = l & 15, l4 = l >> 4;
  const float NEGINF = -__builtin_inff();

  __shared__ __align__(16) u16 Ksm[2][64 * 64];
  __shared__ __align__(16) u16 Vsm[2][64 * 64];
  __shared__ __align__(16) u32 Psm[4][16 * 32];  // per-wave P, XOR-swizzled 16B blocks

  const u16* Qb = Qm + (size_t)bb * S * ldq + h * 64;
  const u16* Kb = Km + (size_t)bb * S * ldq + h * 64;
  const u16* Vtb = vt + (size_t)bh * 64 * 2048;

  auto stageKV = [&](int j, int buf) {
    const int k0 = j * 64;
#pragma unroll
    for (int i = 0; i < 2; ++i) {
      const int s = t + i * 256;
      const int row = s >> 3;
      const int colE = ((s & 7) ^ (row & 7)) * 8;
      GL_LDS16(Kb + (size_t)(k0 + row) * ldq + colE, &Ksm[buf][(s >> 6) * 512]);
      GL_LDS16(Vtb + (size_t)row * 2048 + k0 + colE, &Vsm[buf][(s >> 6) * 512]);
    }
  };

  u32* Pw = &Psm[w][0];
  const u16* Pu = (const u16*)Pw;
  const int h7 = l15 & 7;

  for (int half = 0; half < 2; ++half) {
    const int bx = half ? (31 - p) : p;
    const int q0 = bx * 64;
    __syncthreads();                         // prior half's LDS reads done
    stageKV(0, 0);

    bf16x8 qf[2];
    const int qq = q0 + w * 16 + l15;        // this lane's q-row
#pragma unroll
    for (int c = 0; c < 2; ++c) qf[c] = ld8(Qb + (size_t)qq * ldq + c * 32 + l4 * 8);

    f32x4 accT[4] = {};                      // O^T: dv = nf*16+l4*4+r, q = l15
    float mrow = NEGINF, lrow = 0.f;
    int cur = 0;

    for (int j = 0; j <= bx; ++j) {
      __syncthreads();                       // buf[cur] staged (vmcnt drained)
      if (j < bx) stageKV(j + 1, cur ^ 1);

      // S^T = K @ Q^T  (Q pre-scaled by 1/8): sv[nf][r]: k-row, q-col=l15
      f32x4 sv[4] = {};
      __builtin_amdgcn_s_setprio(1);
#pragma unroll
      for (int c = 0; c < 2; ++c) {
#pragma unroll
        for (int nf = 0; nf < 4; ++nf) {
          const int row = nf * 16 + l15;
          bf16x8 kf = ld8(&Ksm[cur][row * 64 + ((c * 32 + l4 * 8) ^ ((row & 7) * 8))]);
          sv[nf] = __builtin_amdgcn_mfma_f32_16x16x32_bf16(kf, qf[c], sv[nf], 0, 0, 0);
        }
      }
      __builtin_amdgcn_s_setprio(0);

      if (j == bx) {                         // causal mask on diagonal tile
        const int k0 = j * 64;
#pragma unroll
        for (int nf = 0; nf < 4; ++nf) {
          const int kb = k0 + nf * 16 + l4 * 4;
#pragma unroll
          for (int r = 0; r < 4; ++r)
            if (kb + r > qq) sv[nf][r] = NEGINF;
        }
      }

      // row max: in-lane over 16, then xor16/xor32 (2 shuffles)
      f32x4 m4 = vmax4(vmax4(sv[0], sv[1]), vmax4(sv[2], sv[3]));
      float mt = fmaxf(fmaxf(m4[0], m4[1]), fmaxf(m4[2], m4[3]));
      mt = fmaxf(mt, __shfl_xor(mt, 16));
      mt = fmaxf(mt, __shfl_xor(mt, 32));
      const bool skip = __all(mt - mrow <= 8.f);   // defer-max THR=8
      const float mnew = skip ? mrow : fmaxf(mrow, mt);
      if (!skip) {
        const float sf = __expf(mrow - mnew);
        lrow *= sf;
#pragma unroll
        for (int nf = 0; nf < 4; ++nf) accT[nf] *= sf;  // q=l15: lane-local!
        mrow = mnew;
      }
#pragma unroll
      for (int nf = 0; nf < 4; ++nf)
#pragma unroll
        for (int r = 0; r < 4; ++r) sv[nf][r] = __expf(sv[nf][r] - mnew);
      f32x4 s4 = (sv[0] + sv[1]) + (sv[2] + sv[3]);
      float ps = (s4[0] + s4[1]) + (s4[2] + s4[3]);
      ps += __shfl_xor(ps, 16);
      ps += __shfl_xor(ps, 32);
      lrow += ps;

      // pack P -> bf16 pairs -> per-wave LDS (XOR-swizzled 16B blocks)
#pragma unroll
      for (int nf = 0; nf < 4; ++nf) {
        u32 lo, hi;
        asm("v_cvt_pk_bf16_f32 %0, %1, %2" : "=v"(lo) : "v"(sv[nf][0]), "v"(sv[nf][1]));
        asm("v_cvt_pk_bf16_f32 %0, %1, %2" : "=v"(hi) : "v"(sv[nf][2]), "v"(sv[nf][3]));
        const int kw4 = (nf * 2 + (l4 >> 1)) ^ h7;
        const int base = l15 * 32 + kw4 * 4 + (l4 & 1) * 2;
        Pw[base] = lo;
        Pw[base + 1] = hi;
      }

      // O^T += V^T-frag @ P : accT[nf] q=l15, dv=nf*16+l4*4+r
      __builtin_amdgcn_s_setprio(1);
#pragma unroll
      for (int c = 0; c < 2; ++c) {
        bf16x8 pf = ld8(Pu + l15 * 64 + ((c * 4 + l4) ^ h7) * 8);
#pragma unroll
        for (int nf = 0; nf < 4; ++nf) {
          const int row = nf * 16 + l15;
          bf16x8 vf = ld8(&Vsm[cur][row * 64 + ((c * 32 + l4 * 8) ^ ((row & 7) * 8))]);
          accT[nf] = __builtin_amdgcn_mfma_f32_16x16x32_bf16(vf, pf, accT[nf], 0, 0, 0);
        }
      }
      __builtin_amdgcn_s_setprio(0);
      cur ^= 1;
    }

    // epilogue: lane-local divide; 8B packed stores
    const float inv = 1.f / lrow;
    u16* orow = Om + ((size_t)bb * S + qq) * D + h * 64;
#pragma unroll
    for (int nf = 0; nf < 4; ++nf) {
      u16x4 ov;
#pragma unroll
      for (int r = 0; r < 4; ++r) ov[r] = f2bf(accT[nf][r] * inv);
      *(u16x4_a*)(orow + nf * 16 + l4 * 4) = ov;
    }
  }
}

// ---------------- orchestration ----------------
extern "C" void kernel_launch(void* const* d_in, const int* in_sizes, int n_in,
                              void* d_out, int out_size, void* d_ws, size_t ws_size,
                              hipStream_t stream) {
  (void)in_sizes; (void)n_in; (void)out_size; (void)ws_size;
  const float* x    = (const float*)d_in[0];
  const float* W_q  = (const float*)d_in[1];
  const float* W_k  = (const float*)d_in[2];
  const float* W_v  = (const float*)d_in[3];
  const float* W_o  = (const float*)d_in[4];
  const float* W1   = (const float*)d_in[5];
  const float* W2   = (const float*)d_in[6];
  const float* ln1w = (const float*)d_in[7];
  const float* ln1b = (const float*)d_in[8];
  const float* ln2w = (const float*)d_in[9];
  const float* ln2b = (const float*)d_in[10];

  const size_t MB = 1ull << 20;
  char* W = (char*)d_ws;
  u16* wqkv  = (u16*)(W + 0);        //  6 MB  packed [3072][1024] bf16
  u16* wo    = (u16*)(W + 6 * MB);   //  2 MB
  u16* w1b   = (u16*)(W + 8 * MB);   //  8 MB
  u16* w2b   = (u16*)(W + 16 * MB);  //  8 MB
  u16* xn1   = (u16*)(W + 24 * MB);  //  8 MB
  u16* qkv   = (u16*)(W + 32 * MB);  // 24 MB  [4096][3072] bf16 (Q pre-scaled)
  u16* attnb = (u16*)(W + 56 * MB);  //  8 MB
  u16* vt    = (u16*)(W + 64 * MB);  //  8 MB  V^T; dead after attn
  u16* xn2   = (u16*)(W + 64 * MB);  //  8 MB  (shares with vt)
  u16* hbuf  = (u16*)(W + 24 * MB);  // 32 MB, reuses dead xn1+qkv region
  float* x2  = (float*)d_out;        // residual stream lives in d_out

  auto cvt = [&](const float* s, u16* d, int n) {
    int n4 = n >> 2;
    cvt_k<<<dim3((n4 + 255) / 256), dim3(256), 0, stream>>>(s, d, n4);
  };
  cvt(W_q, wqkv, 1 << 20);
  cvt(W_k, wqkv + (1 << 20), 1 << 20);
  cvt(W_v, wqkv + (2 << 20), 1 << 20);
  cvt(W_o, wo, 1 << 20);
  cvt(W1, w1b, 4 << 20);
  cvt(W2, w2b, 4 << 20);

  ln_k<<<dim3(4096), dim3(256), 0, stream>>>(x, ln1w, ln1b, xn1);
  // fused QKV projection (8-phase 256²; Q cols pre-scaled by 1/8)
  gemm8<0><<<dim3(12, 16), dim3(512), 0, stream>>>(xn1, wqkv, qkv, 4096, 3072, 1024, 1024);
  vtr_k<<<dim3(32, 32), dim3(256), 0, stream>>>(qkv + 2048, vt);
  attn_k<<<dim3(16, 32), dim3(256), 0, stream>>>(qkv, qkv + 1024, vt, attnb);
  // x2 = x + attn @ Wo^T   (128² v2: A-LDS + B-in-reg)
  gemm128<<<dim3(8, 32), dim3(512), 0, stream>>>(attnb, wo, x2, x, 4096, 1024, 1024);
  ln_k<<<dim3(4096), dim3(256), 0, stream>>>(x2, ln2w, ln2b, xn2);
  // h = relu(xn2 @ W1^T)  (8-phase 256²)
  gemm8<1><<<dim3(16, 16), dim3(512), 0, stream>>>(xn2, w1b, hbuf, 4096, 4096, 1024, 0);
  // out = x2 + h @ W2^T  (128² v2, in-place residual on d_out)
  gemm128<<<dim3(8, 32), dim3(512), 0, stream>>>(hbuf, w2b, x2, x2, 4096, 1024, 4096);
}

// Round 12
// 232.706 us; speedup vs baseline: 1.1415x; 1.1415x over previous
//
#include <hip/hip_runtime.h>
#include <stdint.h>

typedef unsigned short u16;
typedef unsigned int u32;
typedef __bf16 bf16x8 __attribute__((ext_vector_type(8)));
typedef float f32x4 __attribute__((ext_vector_type(4)));
typedef unsigned short u16x8 __attribute__((ext_vector_type(8)));
typedef unsigned short u16x4 __attribute__((ext_vector_type(4)));
typedef u16x8 u16x8_a __attribute__((may_alias));
typedef u16x4 u16x4_a __attribute__((may_alias));

#define DEV static __device__ __forceinline__

DEV u16 f2bf(float f) {
  unsigned u = __builtin_bit_cast(unsigned, f);
  u += 0x7fffu + ((u >> 16) & 1u);   // RNE
  return (u16)(u >> 16);
}
DEV bf16x8 ld8(const u16* p) {
  u16x8 v = *(const u16x8_a*)p;
  return __builtin_bit_cast(bf16x8, v);
}
DEV f32x4 vmax4(f32x4 a, f32x4 b) {
  f32x4 r;
  r[0] = fmaxf(a[0], b[0]); r[1] = fmaxf(a[1], b[1]);
  r[2] = fmaxf(a[2], b[2]); r[3] = fmaxf(a[3], b[3]);
  return r;
}
// bijective XCD swizzle (m204)
DEV void swz_block(int& bx, int& by) {
  const int gx = gridDim.x;
  const int nwg = gx * gridDim.y;
  int lin = by * gx + bx;
  const int q = nwg >> 3, r = nwg & 7, x = lin & 7, p = lin >> 3;
  lin = (x < r ? x * (q + 1) : r * (q + 1) + (x - r) * q) + p;
  bx = lin % gx; by = lin / gx;
}

#define GL_LDS16(gp, lp)                                                        \
  __builtin_amdgcn_global_load_lds(                                             \
      (const __attribute__((address_space(1))) void*)(gp),                      \
      (__attribute__((address_space(3))) void*)(lp), 16, 0, 0)

#define VMW8 asm volatile("s_waitcnt vmcnt(8)" ::: "memory")
#define VMW4 asm volatile("s_waitcnt vmcnt(4)" ::: "memory")
#define VMW2 asm volatile("s_waitcnt vmcnt(2)" ::: "memory")
#define VMW0 asm volatile("s_waitcnt vmcnt(0)" ::: "memory")
#define BAR  __builtin_amdgcn_s_barrier()

// ---------------- f32 -> bf16 convert ----------------
__global__ __launch_bounds__(256) void cvt_k(const float* __restrict__ s,
                                             u16* __restrict__ d, int n4) {
  int i = blockIdx.x * 256 + threadIdx.x;
  if (i < n4) {
    float4 v = ((const float4*)s)[i];
    u16x4 o;
    o[0] = f2bf(v.x); o[1] = f2bf(v.y); o[2] = f2bf(v.z); o[3] = f2bf(v.w);
    *(u16x4_a*)(d + (size_t)i * 4) = o;
  }
}

// ---------------- f32 partial-sum reduce: d += p ----------------
__global__ __launch_bounds__(256) void red_k(const float* __restrict__ p,
                                             float* __restrict__ d, int n4) {
  int i = blockIdx.x * 256 + threadIdx.x;
  if (i < n4) {
    float4 a = ((const float4*)d)[i];
    float4 b = ((const float4*)p)[i];
    a.x += b.x; a.y += b.y; a.z += b.z; a.w += b.w;
    ((float4*)d)[i] = a;
  }
}

// ---------------- layernorm (f32 in, bf16 out) ----------------
__global__ __launch_bounds__(256) void ln_k(const float* __restrict__ x,
                                            const float* __restrict__ w,
                                            const float* __restrict__ b,
                                            u16* __restrict__ o) {
  const int row = blockIdx.x, t = threadIdx.x;
  const float4 v = ((const float4*)(x + (size_t)row * 1024))[t];
  float s = v.x + v.y + v.z + v.w;
  float q = v.x * v.x + v.y * v.y + v.z * v.z + v.w * v.w;
#pragma unroll
  for (int m = 1; m < 64; m <<= 1) { s += __shfl_xor(s, m); q += __shfl_xor(q, m); }
  __shared__ float ss[4], qq[4];
  if ((t & 63) == 0) { ss[t >> 6] = s; qq[t >> 6] = q; }
  __syncthreads();
  s = ss[0] + ss[1] + ss[2] + ss[3];
  q = qq[0] + qq[1] + qq[2] + qq[3];
  const float mean = s * (1.f / 1024.f);
  const float var = q * (1.f / 1024.f) - mean * mean;
  const float rstd = rsqrtf(var + 1e-5f);
  const float4 wv = ((const float4*)w)[t];
  const float4 bv = ((const float4*)b)[t];
  u16x4 ov;
  ov[0] = f2bf((v.x - mean) * rstd * wv.x + bv.x);
  ov[1] = f2bf((v.y - mean) * rstd * wv.y + bv.y);
  ov[2] = f2bf((v.z - mean) * rstd * wv.z + bv.z);
  ov[3] = f2bf((v.w - mean) * rstd * wv.w + bv.w);
  *(u16x4_a*)(o + (size_t)row * 1024 + t * 4) = ov;
}

// ---------------- V transpose ----------------
__global__ __launch_bounds__(256) void vtr_k(const u16* __restrict__ qkvV,
                                             u16* __restrict__ vt) {
  __shared__ u16 T[64][65];
  const int st = blockIdx.x, bh = blockIdx.y;
  const int b = bh >> 4, h = bh & 15;
  const int t = threadIdx.x;
  const u16* src = qkvV + ((size_t)(b * 2048 + st * 64)) * 3072 + h * 64;
  const int r = t >> 2, c0 = (t & 3) * 16;
  u16x8 a0 = *(const u16x8_a*)(src + (size_t)r * 3072 + c0);
  u16x8 a1 = *(const u16x8_a*)(src + (size_t)r * 3072 + c0 + 8);
#pragma unroll
  for (int e = 0; e < 8; ++e) { T[r][c0 + e] = a0[e]; T[r][c0 + 8 + e] = a1[e]; }
  __syncthreads();
  const int d = t >> 2, s0 = (t & 3) * 16;
  u16x8 o0, o1;
#pragma unroll
  for (int e = 0; e < 8; ++e) { o0[e] = T[s0 + e][d]; o1[e] = T[s0 + 8 + e][d]; }
  u16* dst = vt + ((size_t)bh * 64 + d) * 2048 + (size_t)st * 64 + s0;
  *(u16x8_a*)dst = o0;
  *(u16x8_a*)(dst + 8) = o1;
}

// ================= 256x256 8-phase GEMM, rolling counted-vmcnt schedule =================
DEV void stage_op(const u16* __restrict__ G, int K, int kk, u16* lds, int set,
                  int isB, int w, int l) {
#pragma unroll
  for (int i = 0; i < 2; ++i) {
    const int c = i * 8 + w;                 // chunk 0..15 (1KB, 8 rows)
    int rb;
    if (!isB) { const int lr = c * 8; rb = (lr < 64 ? lr : lr + 64) + set * 64; }
    else      { rb = (c >> 2) * 64 + set * 32 + (c & 3) * 8; }
    const int row = rb + (l >> 3);
    const int c8 = (l & 7) ^ (row & 7);      // inverse-swizzled source col
    GL_LDS16(G + (size_t)row * K + kk + c8 * 8, lds + rb * 64);
  }
}
DEV void rdA(const u16* as, int wr, int mh, int l15, int l4, bf16x8 af[4][2]) {
#pragma unroll
  for (int f = 0; f < 4; ++f) {
    const int row = wr * 128 + mh * 64 + f * 16 + l15;
#pragma unroll
    for (int ks = 0; ks < 2; ++ks) {
      const int c8 = (ks * 4 + l4) ^ (row & 7);
      af[f][ks] = ld8(as + row * 64 + c8 * 8);
    }
  }
}
DEV void rdB(const u16* bs, int wc, int nh, int l15, int l4, bf16x8 bf_[2][2]) {
#pragma unroll
  for (int g = 0; g < 2; ++g) {
    const int row = wc * 64 + nh * 32 + g * 16 + l15;
#pragma unroll
    for (int ks = 0; ks < 2; ++ks) {
      const int c8 = (ks * 4 + l4) ^ (row & 7);
      bf_[g][ks] = ld8(bs + row * 64 + c8 * 8);
    }
  }
}

#define MFMA16(mh, nh)                                                          \
  __builtin_amdgcn_s_setprio(1);                                                \
  _Pragma("unroll")                                                             \
  for (int f = 0; f < 4; ++f) {                                                 \
    _Pragma("unroll")                                                           \
    for (int g = 0; g < 2; ++g) {                                               \
      f32x4& a_ = acc[(mh) * 4 + f][(nh) * 2 + g];                              \
      a_ = __builtin_amdgcn_mfma_f32_16x16x32_bf16(af[f][0], bfr[g][0], a_, 0, 0, 0); \
      a_ = __builtin_amdgcn_mfma_f32_16x16x32_bf16(af[f][1], bfr[g][1], a_, 0, 0, 0); \
    }                                                                           \
  }                                                                             \
  __builtin_amdgcn_s_setprio(0);

template <int EPI>
__global__ __launch_bounds__(512, 2) void gemm8(const u16* __restrict__ A,
                                                const u16* __restrict__ Bw,
                                                u16* __restrict__ Cp,
                                                int M, int N, int K, int qcols) {
  __shared__ __align__(16) u16 As[2][256 * 64];
  __shared__ __align__(16) u16 Bs[2][256 * 64];
  const int t = threadIdx.x, w = t >> 6, l = t & 63;
  const int l15 = l & 15, l4 = l >> 4;
  const int wr = w >> 2, wc = w & 3;
  int bx = blockIdx.x, by = blockIdx.y;
  swz_block(bx, by);
  const int bm0 = by * 256, bn0 = bx * 256;
  const u16* Ab = A + (size_t)bm0 * K;
  const u16* Bb = Bw + (size_t)bn0 * K;

  f32x4 acc[8][4] = {};
  stage_op(Ab, K, 0, As[0], 0, 0, w, l);
  stage_op(Bb, K, 0, Bs[0], 0, 1, w, l);
  stage_op(Bb, K, 0, Bs[0], 1, 1, w, l);
  stage_op(Ab, K, 0, As[0], 1, 0, w, l);
  VMW4;                                    // hA0,hB0 resident; {hB1,hA1} in flight
  BAR;

  const int nk = K >> 6;
  int cur = 0;
  bf16x8 af[4][2], bfr[2][2];
  for (int kt = 0; kt < nk; ++kt) {
    const int kn = (kt + 1) << 6;
    const bool more = (kt + 1 < nk);
    u16* An = As[cur ^ 1];
    u16* Bn = Bs[cur ^ 1];
    // ---- phase A: quad(0,0); prefetch hA0(t+1) ----
    rdA(As[cur], wr, 0, l15, l4, af);
    rdB(Bs[cur], wc, 0, l15, l4, bfr);
    if (more) stage_op(Ab, K, kn, An, 0, 0, w, l);
    BAR;
    MFMA16(0, 0)
    if (more) { VMW4; } else { VMW2; }     // drain hB1(kt) for phase B
    BAR;
    // ---- phase B: quad(0,1); prefetch hB0(t+1) ----
    rdB(Bs[cur], wc, 1, l15, l4, bfr);
    if (more) stage_op(Bb, K, kn, Bn, 0, 1, w, l);
    BAR;
    MFMA16(0, 1)
    if (more) { VMW4; } else { VMW0; }     // drain hA1(kt) for phase C
    BAR;
    // ---- phase C: quad(1,1); prefetch hB1(t+1) ----
    rdA(As[cur], wr, 1, l15, l4, af);
    if (more) stage_op(Bb, K, kn, Bn, 1, 1, w, l);
    BAR;
    MFMA16(1, 1)
    BAR;
    // ---- phase D: quad(1,0); prefetch hA1(t+1) ----
    rdB(Bs[cur], wc, 0, l15, l4, bfr);
    if (more) stage_op(Ab, K, kn, An, 1, 0, w, l);
    BAR;
    MFMA16(1, 0)
    if (more) { VMW4; }                    // hA0,hB0(t+1) landed
    BAR;
    cur ^= 1;
  }

#pragma unroll
  for (int m = 0; m < 8; ++m) {
    const int row0 = bm0 + wr * 128 + m * 16 + l4 * 4;
#pragma unroll
    for (int n = 0; n < 4; ++n) {
      const int col = bn0 + wc * 64 + n * 16 + l15;
      const float qs = (col < qcols) ? 0.125f : 1.f;
#pragma unroll
      for (int r = 0; r < 4; ++r) {
        float v = acc[m][n][r] * qs;
        if constexpr (EPI == 1) v = v > 0.f ? v : 0.f;
        Cp[(size_t)(row0 + r) * N + col] = f2bf(v);
      }
    }
  }
}

// ============ 128x128 deep-pipeline GEMM (3-buf, vmcnt(8)): C = res + A @ Bw^T ============
// r9-proven version (71us FFN2 / ~25us Wo). 1 block/CU.
__global__ __launch_bounds__(512, 1) void gemm128(const u16* __restrict__ A,
                                                  const u16* __restrict__ Bw,
                                                  float* __restrict__ C,
                                                  const float* __restrict__ res,
                                                  int M, int N, int K) {
  __shared__ __align__(16) u16 As[3][128 * 64];
  __shared__ __align__(16) u16 Bs[3][128 * 64];
  const int t = threadIdx.x, w = t >> 6, l = t & 63;
  const int l15 = l & 15, l4 = l >> 4;
  const int wr = w >> 2, wc = w & 3;              // 2M x 4N
  int bx = blockIdx.x, by = blockIdx.y;
  swz_block(bx, by);
  const int bm0 = by * 128, bn0 = bx * 128;
  const u16* Ab = A + (size_t)bm0 * K;
  const u16* Bb = Bw + (size_t)bn0 * K;

  auto stg = [&](const u16* __restrict__ G, u16* lds, int kk) {
#pragma unroll
    for (int i = 0; i < 2; ++i) {
      const int c = i * 8 + w;                    // 16 chunks x 8 rows
      const int row = c * 8 + (l >> 3);
      const int c8 = (l & 7) ^ (row & 7);
      GL_LDS16(G + (size_t)row * K + kk + c8 * 8, lds + c * 512);
    }
  };

  f32x4 acc[4][2] = {};
  stg(Ab, As[0], 0);  stg(Bb, Bs[0], 0);
  stg(Ab, As[1], 64); stg(Bb, Bs[1], 64);
  const int nk = K >> 6;
  for (int kt = 0; kt < nk; ++kt) {
    const int cur = kt % 3;
    if (kt + 2 < nk) {
      const int nxt = (kt + 2) % 3;
      const int kk = (kt + 2) << 6;
      stg(Ab, As[nxt], kk);
      stg(Bb, Bs[nxt], kk);
    }
    const int rem = nk - 1 - kt;
    if (rem >= 2) { VMW8; } else if (rem == 1) { VMW4; } else { VMW0; }
    BAR;
    bf16x8 af[4][2], bfr[2][2];
#pragma unroll
    for (int f = 0; f < 4; ++f) {
      const int row = wr * 64 + f * 16 + l15;
#pragma unroll
      for (int ks = 0; ks < 2; ++ks)
        af[f][ks] = ld8(&As[cur][row * 64 + (((ks * 4 + l4) ^ (row & 7)) * 8)]);
    }
#pragma unroll
    for (int g = 0; g < 2; ++g) {
      const int row = wc * 32 + g * 16 + l15;
#pragma unroll
      for (int ks = 0; ks < 2; ++ks)
        bfr[g][ks] = ld8(&Bs[cur][row * 64 + (((ks * 4 + l4) ^ (row & 7)) * 8)]);
    }
    __builtin_amdgcn_s_setprio(1);
#pragma unroll
    for (int f = 0; f < 4; ++f)
#pragma unroll
      for (int g = 0; g < 2; ++g) {
        acc[f][g] = __builtin_amdgcn_mfma_f32_16x16x32_bf16(af[f][0], bfr[g][0], acc[f][g], 0, 0, 0);
        acc[f][g] = __builtin_amdgcn_mfma_f32_16x16x32_bf16(af[f][1], bfr[g][1], acc[f][g], 0, 0, 0);
      }
    __builtin_amdgcn_s_setprio(0);
    BAR;
  }

#pragma unroll
  for (int f = 0; f < 4; ++f) {
    const int row0 = bm0 + wr * 64 + f * 16 + l4 * 4;
#pragma unroll
    for (int g = 0; g < 2; ++g) {
      const int col = bn0 + wc * 32 + g * 16 + l15;
#pragma unroll
      for (int r = 0; r < 4; ++r) {
        const size_t idx = (size_t)(row0 + r) * N + col;
        C[idx] = res[idx] + acc[f][g][r];
      }
    }
  }
}

// ====== 128x128 split-K GEMM (2-buf, m97-style, 2 blocks/CU): kz0 -> C=res+acc, kz1 -> P=acc ======
__global__ __launch_bounds__(512, 4) void gemm128s(const u16* __restrict__ A,
                                                   const u16* __restrict__ Bw,
                                                   float* __restrict__ C,
                                                   float* __restrict__ P,
                                                   const float* __restrict__ res,
                                                   int M, int N, int K, int Kc) {
  __shared__ __align__(16) u16 As[2][128 * 64];
  __shared__ __align__(16) u16 Bs[2][128 * 64];
  const int t = threadIdx.x, w = t >> 6, l = t & 63;
  const int l15 = l & 15, l4 = l >> 4;
  const int wr = w >> 2, wc = w & 3;              // 2M x 4N, wave 64x32
  int bx = blockIdx.x, by = blockIdx.y;
  swz_block(bx, by);
  const int kz = blockIdx.z;
  const int bm0 = by * 128, bn0 = bx * 128;
  const u16* Ab = A + (size_t)bm0 * K + (size_t)kz * Kc;
  const u16* Bb = Bw + (size_t)bn0 * K + (size_t)kz * Kc;

  auto stg = [&](const u16* __restrict__ G, u16* lds, int kk) {
#pragma unroll
    for (int i = 0; i < 2; ++i) {
      const int c = i * 8 + w;                    // 16 chunks x 8 rows
      const int row = c * 8 + (l >> 3);
      const int c8 = (l & 7) ^ (row & 7);
      GL_LDS16(G + (size_t)row * K + kk + c8 * 8, lds + c * 512);
    }
  };

  f32x4 acc[4][2] = {};
  stg(Ab, As[0], 0); stg(Bb, Bs[0], 0);
  const int nk = Kc >> 6;
  int cur = 0;
  for (int kt = 0; kt < nk; ++kt) {
    __syncthreads();                              // buf[cur] resident (vmcnt drained)
    if (kt + 1 < nk) {
      stg(Ab, As[cur ^ 1], (kt + 1) << 6);
      stg(Bb, Bs[cur ^ 1], (kt + 1) << 6);
    }
    bf16x8 af[4][2], bfr[2][2];
#pragma unroll
    for (int f = 0; f < 4; ++f) {
      const int row = wr * 64 + f * 16 + l15;
#pragma unroll
      for (int ks = 0; ks < 2; ++ks)
        af[f][ks] = ld8(&As[cur][row * 64 + (((ks * 4 + l4) ^ (row & 7)) * 8)]);
    }
#pragma unroll
    for (int g = 0; g < 2; ++g) {
      const int row = wc * 32 + g * 16 + l15;
#pragma unroll
      for (int ks = 0; ks < 2; ++ks)
        bfr[g][ks] = ld8(&Bs[cur][row * 64 + (((ks * 4 + l4) ^ (row & 7)) * 8)]);
    }
    __builtin_amdgcn_s_setprio(1);
#pragma unroll
    for (int f = 0; f < 4; ++f)
#pragma unroll
      for (int g = 0; g < 2; ++g) {
        acc[f][g] = __builtin_amdgcn_mfma_f32_16x16x32_bf16(af[f][0], bfr[g][0], acc[f][g], 0, 0, 0);
        acc[f][g] = __builtin_amdgcn_mfma_f32_16x16x32_bf16(af[f][1], bfr[g][1], acc[f][g], 0, 0, 0);
      }
    __builtin_amdgcn_s_setprio(0);
    __syncthreads();                              // reads of buf[cur] done
    cur ^= 1;
  }

#pragma unroll
  for (int f = 0; f < 4; ++f) {
    const int row0 = bm0 + wr * 64 + f * 16 + l4 * 4;
#pragma unroll
    for (int g = 0; g < 2; ++g) {
      const int col = bn0 + wc * 32 + g * 16 + l15;
#pragma unroll
      for (int r = 0; r < 4; ++r) {
        const size_t idx = (size_t)(row0 + r) * N + col;
        if (kz == 0) C[idx] = res[idx] + acc[f][g][r];
        else         P[idx] = acc[f][g][r];
      }
    }
  }
}

// ---------------- causal flash attention v5: swapped QK^T, in-register softmax ----------
__global__ __launch_bounds__(256) void attn_k(const u16* __restrict__ Qm,
                                              const u16* __restrict__ Km,
                                              const u16* __restrict__ vt,
                                              u16* __restrict__ Om) {
  const int S = 2048, D = 1024, ldq = 3072;
  int p = blockIdx.x, bh = blockIdx.y;
  swz_block(p, bh);                          // same-bh pairs grouped per XCD
  const int bb = bh >> 4, h = bh & 15;
  const int t = threadIdx.x, w = t >> 6, l = t & 63, l15 = l & 15, l4 = l >> 4;
  const float NEGINF = -__builtin_inff();

  __shared__ __align__(16) u16 Ksm[2][64 * 64];
  __shared__ __align__(16) u16 Vsm[2][64 * 64];
  __shared__ __align__(16) u32 Psm[4][16 * 32];  // per-wave P, XOR-swizzled 16B blocks

  const u16* Qb = Qm + (size_t)bb * S * ldq + h * 64;
  const u16* Kb = Km + (size_t)bb * S * ldq + h * 64;
  const u16* Vtb = vt + (size_t)bh * 64 * 2048;

  auto stageKV = [&](int j, int buf) {
    const int k0 = j * 64;
#pragma unroll
    for (int i = 0; i < 2; ++i) {
      const int s = t + i * 256;
      const int row = s >> 3;
      const int colE = ((s & 7) ^ (row & 7)) * 8;
      GL_LDS16(Kb + (size_t)(k0 + row) * ldq + colE, &Ksm[buf][(s >> 6) * 512]);
      GL_LDS16(Vtb + (size_t)row * 2048 + k0 + colE, &Vsm[buf][(s >> 6) * 512]);
    }
  };

  u32* Pw = &Psm[w][0];
  const u16* Pu = (const u16*)Pw;
  const int h7 = l15 & 7;

  for (int half = 0; half < 2; ++half) {
    const int bx = half ? (31 - p) : p;
    const int q0 = bx * 64;
    __syncthreads();                         // prior half's LDS reads done
    stageKV(0, 0);

    bf16x8 qf[2];
    const int qq = q0 + w * 16 + l15;        // this lane's q-row
#pragma unroll
    for (int c = 0; c < 2; ++c) qf[c] = ld8(Qb + (size_t)qq * ldq + c * 32 + l4 * 8);

    f32x4 accT[4] = {};                      // O^T: dv = nf*16+l4*4+r, q = l15
    float mrow = NEGINF, lrow = 0.f;
    int cur = 0;

    for (int j = 0; j <= bx; ++j) {
      __syncthreads();                       // buf[cur] staged (vmcnt drained)
      if (j < bx) stageKV(j + 1, cur ^ 1);

      // S^T = K @ Q^T  (Q pre-scaled by 1/8): sv[nf][r]: k-row, q-col=l15
      f32x4 sv[4] = {};
      __builtin_amdgcn_s_setprio(1);
#pragma unroll
      for (int c = 0; c < 2; ++c) {
#pragma unroll
        for (int nf = 0; nf < 4; ++nf) {
          const int row = nf * 16 + l15;
          bf16x8 kf = ld8(&Ksm[cur][row * 64 + ((c * 32 + l4 * 8) ^ ((row & 7) * 8))]);
          sv[nf] = __builtin_amdgcn_mfma_f32_16x16x32_bf16(kf, qf[c], sv[nf], 0, 0, 0);
        }
      }
      __builtin_amdgcn_s_setprio(0);

      if (j == bx) {                         // causal mask on diagonal tile
        const int k0 = j * 64;
#pragma unroll
        for (int nf = 0; nf < 4; ++nf) {
          const int kb = k0 + nf * 16 + l4 * 4;
#pragma unroll
          for (int r = 0; r < 4; ++r)
            if (kb + r > qq) sv[nf][r] = NEGINF;
        }
      }

      // row max: in-lane over 16, then xor16/xor32 (2 shuffles)
      f32x4 m4 = vmax4(vmax4(sv[0], sv[1]), vmax4(sv[2], sv[3]));
      float mt = fmaxf(fmaxf(m4[0], m4[1]), fmaxf(m4[2], m4[3]));
      mt = fmaxf(mt, __shfl_xor(mt, 16));
      mt = fmaxf(mt, __shfl_xor(mt, 32));
      const bool skip = __all(mt - mrow <= 8.f);   // defer-max THR=8
      const float mnew = skip ? mrow : fmaxf(mrow, mt);
      if (!skip) {
        const float sf = __expf(mrow - mnew);
        lrow *= sf;
#pragma unroll
        for (int nf = 0; nf < 4; ++nf) accT[nf] *= sf;  // q=l15: lane-local!
        mrow = mnew;
      }
#pragma unroll
      for (int nf = 0; nf < 4; ++nf)
#pragma unroll
        for (int r = 0; r < 4; ++r) sv[nf][r] = __expf(sv[nf][r] - mnew);
      f32x4 s4 = (sv[0] + sv[1]) + (sv[2] + sv[3]);
      float ps = (s4[0] + s4[1]) + (s4[2] + s4[3]);
      ps += __shfl_xor(ps, 16);
      ps += __shfl_xor(ps, 32);
      lrow += ps;

      // pack P -> bf16 pairs -> per-wave LDS (XOR-swizzled 16B blocks)
#pragma unroll
      for (int nf = 0; nf < 4; ++nf) {
        u32 lo, hi;
        asm("v_cvt_pk_bf16_f32 %0, %1, %2" : "=v"(lo) : "v"(sv[nf][0]), "v"(sv[nf][1]));
        asm("v_cvt_pk_bf16_f32 %0, %1, %2" : "=v"(hi) : "v"(sv[nf][2]), "v"(sv[nf][3]));
        const int kw4 = (nf * 2 + (l4 >> 1)) ^ h7;
        const int base = l15 * 32 + kw4 * 4 + (l4 & 1) * 2;
        Pw[base] = lo;
        Pw[base + 1] = hi;
      }

      // O^T += V^T-frag @ P : accT[nf] q=l15, dv=nf*16+l4*4+r
      __builtin_amdgcn_s_setprio(1);
#pragma unroll
      for (int c = 0; c < 2; ++c) {
        bf16x8 pf = ld8(Pu + l15 * 64 + ((c * 4 + l4) ^ h7) * 8);
#pragma unroll
        for (int nf = 0; nf < 4; ++nf) {
          const int row = nf * 16 + l15;
          bf16x8 vf = ld8(&Vsm[cur][row * 64 + ((c * 32 + l4 * 8) ^ ((row & 7) * 8))]);
          accT[nf] = __builtin_amdgcn_mfma_f32_16x16x32_bf16(vf, pf, accT[nf], 0, 0, 0);
        }
      }
      __builtin_amdgcn_s_setprio(0);
      cur ^= 1;
    }

    // epilogue: lane-local divide; 8B packed stores
    const float inv = 1.f / lrow;
    u16* orow = Om + ((size_t)bb * S + qq) * D + h * 64;
#pragma unroll
    for (int nf = 0; nf < 4; ++nf) {
      u16x4 ov;
#pragma unroll
      for (int r = 0; r < 4; ++r) ov[r] = f2bf(accT[nf][r] * inv);
      *(u16x4_a*)(orow + nf * 16 + l4 * 4) = ov;
    }
  }
}

// ---------------- orchestration ----------------
extern "C" void kernel_launch(void* const* d_in, const int* in_sizes, int n_in,
                              void* d_out, int out_size, void* d_ws, size_t ws_size,
                              hipStream_t stream) {
  (void)in_sizes; (void)n_in; (void)out_size; (void)ws_size;
  const float* x    = (const float*)d_in[0];
  const float* W_q  = (const float*)d_in[1];
  const float* W_k  = (const float*)d_in[2];
  const float* W_v  = (const float*)d_in[3];
  const float* W_o  = (const float*)d_in[4];
  const float* W1   = (const float*)d_in[5];
  const float* W2   = (const float*)d_in[6];
  const float* ln1w = (const float*)d_in[7];
  const float* ln1b = (const float*)d_in[8];
  const float* ln2w = (const float*)d_in[9];
  const float* ln2b = (const float*)d_in[10];

  const size_t MB = 1ull << 20;
  char* W = (char*)d_ws;
  u16* wqkv  = (u16*)(W + 0);        //  6 MB  packed [3072][1024] bf16
  u16* wo    = (u16*)(W + 6 * MB);   //  2 MB
  u16* w1b   = (u16*)(W + 8 * MB);   //  8 MB
  u16* w2b   = (u16*)(W + 16 * MB);  //  8 MB
  u16* xn1   = (u16*)(W + 24 * MB);  //  8 MB
  u16* qkv   = (u16*)(W + 32 * MB);  // 24 MB  [4096][3072] bf16 (Q pre-scaled)
  u16* attnb = (u16*)(W + 56 * MB);  //  8 MB
  u16* vt    = (u16*)(W + 64 * MB);  //  8 MB  V^T; dead after attn
  u16* xn2   = (u16*)(W + 64 * MB);  //  8 MB  (shares with vt)
  u16* hbuf  = (u16*)(W + 24 * MB);  // 32 MB, reuses dead xn1+qkv region
  float* fpart = (float*)(W + 56 * MB); // 16 MB f32 split-K partial (attnb/vt dead)
  float* x2  = (float*)d_out;        // residual stream lives in d_out

  auto cvt = [&](const float* s, u16* d, int n) {
    int n4 = n >> 2;
    cvt_k<<<dim3((n4 + 255) / 256), dim3(256), 0, stream>>>(s, d, n4);
  };
  cvt(W_q, wqkv, 1 << 20);
  cvt(W_k, wqkv + (1 << 20), 1 << 20);
  cvt(W_v, wqkv + (2 << 20), 1 << 20);
  cvt(W_o, wo, 1 << 20);
  cvt(W1, w1b, 4 << 20);
  cvt(W2, w2b, 4 << 20);

  ln_k<<<dim3(4096), dim3(256), 0, stream>>>(x, ln1w, ln1b, xn1);
  // fused QKV projection (8-phase 256²; Q cols pre-scaled by 1/8)
  gemm8<0><<<dim3(12, 16), dim3(512), 0, stream>>>(xn1, wqkv, qkv, 4096, 3072, 1024, 1024);
  vtr_k<<<dim3(32, 32), dim3(256), 0, stream>>>(qkv + 2048, vt);
  attn_k<<<dim3(16, 32), dim3(256), 0, stream>>>(qkv, qkv + 1024, vt, attnb);
  // x2 = x + attn @ Wo^T   (128² 3-buf, residual fused)
  gemm128<<<dim3(8, 32), dim3(512), 0, stream>>>(attnb, wo, x2, x, 4096, 1024, 1024);
  ln_k<<<dim3(4096), dim3(256), 0, stream>>>(x2, ln2w, ln2b, xn2);
  // h = relu(xn2 @ W1^T)  (8-phase 256²)
  gemm8<1><<<dim3(16, 16), dim3(512), 0, stream>>>(xn2, w1b, hbuf, 4096, 4096, 1024, 0);
  // FFN2 split-K=2: kz0 -> d_out = x2 + acc0 (in-place), kz1 -> fpart = acc1
  gemm128s<<<dim3(8, 32, 2), dim3(512), 0, stream>>>(hbuf, w2b, x2, fpart, x2,
                                                     4096, 1024, 4096, 2048);
  // d_out += fpart
  red_k<<<dim3(4096), dim3(256), 0, stream>>>(fpart, x2, 1 << 20);
}

// Round 13
// 231.355 us; speedup vs baseline: 1.1482x; 1.0058x over previous
//
#include <hip/hip_runtime.h>
#include <stdint.h>

typedef unsigned short u16;
typedef unsigned int u32;
typedef __bf16 bf16x8 __attribute__((ext_vector_type(8)));
typedef float f32x4 __attribute__((ext_vector_type(4)));
typedef unsigned short u16x8 __attribute__((ext_vector_type(8)));
typedef unsigned short u16x4 __attribute__((ext_vector_type(4)));
typedef u16x8 u16x8_a __attribute__((may_alias));
typedef u16x4 u16x4_a __attribute__((may_alias));

#define DEV static __device__ __forceinline__

DEV u16 f2bf(float f) {
  unsigned u = __builtin_bit_cast(unsigned, f);
  u += 0x7fffu + ((u >> 16) & 1u);   // RNE
  return (u16)(u >> 16);
}
DEV bf16x8 ld8(const u16* p) {
  u16x8 v = *(const u16x8_a*)p;
  return __builtin_bit_cast(bf16x8, v);
}
DEV f32x4 vmax4(f32x4 a, f32x4 b) {
  f32x4 r;
  r[0] = fmaxf(a[0], b[0]); r[1] = fmaxf(a[1], b[1]);
  r[2] = fmaxf(a[2], b[2]); r[3] = fmaxf(a[3], b[3]);
  return r;
}
// bijective XCD swizzle (m204)
DEV void swz_block(int& bx, int& by) {
  const int gx = gridDim.x;
  const int nwg = gx * gridDim.y;
  int lin = by * gx + bx;
  const int q = nwg >> 3, r = nwg & 7, x = lin & 7, p = lin >> 3;
  lin = (x < r ? x * (q + 1) : r * (q + 1) + (x - r) * q) + p;
  bx = lin % gx; by = lin / gx;
}

#define GL_LDS16(gp, lp)                                                        \
  __builtin_amdgcn_global_load_lds(                                             \
      (const __attribute__((address_space(1))) void*)(gp),                      \
      (__attribute__((address_space(3))) void*)(lp), 16, 0, 0)

#define VMW4 asm volatile("s_waitcnt vmcnt(4)" ::: "memory")
#define VMW2 asm volatile("s_waitcnt vmcnt(2)" ::: "memory")
#define VMW0 asm volatile("s_waitcnt vmcnt(0)" ::: "memory")
#define BAR  __builtin_amdgcn_s_barrier()

// ---------------- fused f32 -> bf16 convert for all 6 weights (one launch) ----------------
struct Cvt6 {
  const float* s[6];
  u16* d[6];
  int n4[6];
};
__global__ __launch_bounds__(256) void cvt6_k(Cvt6 c) {
  const int yi = blockIdx.y;
  const int i = blockIdx.x * 256 + threadIdx.x;
  if (i < c.n4[yi]) {
    float4 v = ((const float4*)c.s[yi])[i];
    u16x4 o;
    o[0] = f2bf(v.x); o[1] = f2bf(v.y); o[2] = f2bf(v.z); o[3] = f2bf(v.w);
    *(u16x4_a*)(c.d[yi] + (size_t)i * 4) = o;
  }
}

// ---------------- layernorm (f32 in, bf16 out) ----------------
__global__ __launch_bounds__(256) void ln_k(const float* __restrict__ x,
                                            const float* __restrict__ w,
                                            const float* __restrict__ b,
                                            u16* __restrict__ o) {
  const int row = blockIdx.x, t = threadIdx.x;
  const float4 v = ((const float4*)(x + (size_t)row * 1024))[t];
  float s = v.x + v.y + v.z + v.w;
  float q = v.x * v.x + v.y * v.y + v.z * v.z + v.w * v.w;
#pragma unroll
  for (int m = 1; m < 64; m <<= 1) { s += __shfl_xor(s, m); q += __shfl_xor(q, m); }
  __shared__ float ss[4], qq[4];
  if ((t & 63) == 0) { ss[t >> 6] = s; qq[t >> 6] = q; }
  __syncthreads();
  s = ss[0] + ss[1] + ss[2] + ss[3];
  q = qq[0] + qq[1] + qq[2] + qq[3];
  const float mean = s * (1.f / 1024.f);
  const float var = q * (1.f / 1024.f) - mean * mean;
  const float rstd = rsqrtf(var + 1e-5f);
  const float4 wv = ((const float4*)w)[t];
  const float4 bv = ((const float4*)b)[t];
  u16x4 ov;
  ov[0] = f2bf((v.x - mean) * rstd * wv.x + bv.x);
  ov[1] = f2bf((v.y - mean) * rstd * wv.y + bv.y);
  ov[2] = f2bf((v.z - mean) * rstd * wv.z + bv.z);
  ov[3] = f2bf((v.w - mean) * rstd * wv.w + bv.w);
  *(u16x4_a*)(o + (size_t)row * 1024 + t * 4) = ov;
}

// ---------------- V transpose ----------------
__global__ __launch_bounds__(256) void vtr_k(const u16* __restrict__ qkvV,
                                             u16* __restrict__ vt) {
  __shared__ u16 T[64][65];
  const int st = blockIdx.x, bh = blockIdx.y;
  const int b = bh >> 4, h = bh & 15;
  const int t = threadIdx.x;
  const u16* src = qkvV + ((size_t)(b * 2048 + st * 64)) * 3072 + h * 64;
  const int r = t >> 2, c0 = (t & 3) * 16;
  u16x8 a0 = *(const u16x8_a*)(src + (size_t)r * 3072 + c0);
  u16x8 a1 = *(const u16x8_a*)(src + (size_t)r * 3072 + c0 + 8);
#pragma unroll
  for (int e = 0; e < 8; ++e) { T[r][c0 + e] = a0[e]; T[r][c0 + 8 + e] = a1[e]; }
  __syncthreads();
  const int d = t >> 2, s0 = (t & 3) * 16;
  u16x8 o0, o1;
#pragma unroll
  for (int e = 0; e < 8; ++e) { o0[e] = T[s0 + e][d]; o1[e] = T[s0 + 8 + e][d]; }
  u16* dst = vt + ((size_t)bh * 64 + d) * 2048 + (size_t)st * 64 + s0;
  *(u16x8_a*)dst = o0;
  *(u16x8_a*)(dst + 8) = o1;
}

// ================= 256x256 8-phase GEMM, rolling counted-vmcnt schedule =================
DEV void stage_op(const u16* __restrict__ G, int K, int kk, u16* lds, int set,
                  int isB, int w, int l) {
#pragma unroll
  for (int i = 0; i < 2; ++i) {
    const int c = i * 8 + w;                 // chunk 0..15 (1KB, 8 rows)
    int rb;
    if (!isB) { const int lr = c * 8; rb = (lr < 64 ? lr : lr + 64) + set * 64; }
    else      { rb = (c >> 2) * 64 + set * 32 + (c & 3) * 8; }
    const int row = rb + (l >> 3);
    const int c8 = (l & 7) ^ (row & 7);      // inverse-swizzled source col
    GL_LDS16(G + (size_t)row * K + kk + c8 * 8, lds + rb * 64);
  }
}
DEV void rdA(const u16* as, int wr, int mh, int l15, int l4, bf16x8 af[4][2]) {
#pragma unroll
  for (int f = 0; f < 4; ++f) {
    const int row = wr * 128 + mh * 64 + f * 16 + l15;
#pragma unroll
    for (int ks = 0; ks < 2; ++ks) {
      const int c8 = (ks * 4 + l4) ^ (row & 7);
      af[f][ks] = ld8(as + row * 64 + c8 * 8);
    }
  }
}
DEV void rdB(const u16* bs, int wc, int nh, int l15, int l4, bf16x8 bf_[2][2]) {
#pragma unroll
  for (int g = 0; g < 2; ++g) {
    const int row = wc * 64 + nh * 32 + g * 16 + l15;
#pragma unroll
    for (int ks = 0; ks < 2; ++ks) {
      const int c8 = (ks * 4 + l4) ^ (row & 7);
      bf_[g][ks] = ld8(bs + row * 64 + c8 * 8);
    }
  }
}

#define MFMA16(mh, nh)                                                          \
  __builtin_amdgcn_s_setprio(1);                                                \
  _Pragma("unroll")                                                             \
  for (int f = 0; f < 4; ++f) {                                                 \
    _Pragma("unroll")                                                           \
    for (int g = 0; g < 2; ++g) {                                               \
      f32x4& a_ = acc[(mh) * 4 + f][(nh) * 2 + g];                              \
      a_ = __builtin_amdgcn_mfma_f32_16x16x32_bf16(af[f][0], bfr[g][0], a_, 0, 0, 0); \
      a_ = __builtin_amdgcn_mfma_f32_16x16x32_bf16(af[f][1], bfr[g][1], a_, 0, 0, 0); \
    }                                                                           \
  }                                                                             \
  __builtin_amdgcn_s_setprio(0);

template <int EPI>
__global__ __launch_bounds__(512, 2) void gemm8(const u16* __restrict__ A,
                                                const u16* __restrict__ Bw,
                                                u16* __restrict__ Cp,
                                                int M, int N, int K, int qcols) {
  __shared__ __align__(16) u16 As[2][256 * 64];
  __shared__ __align__(16) u16 Bs[2][256 * 64];
  const int t = threadIdx.x, w = t >> 6, l = t & 63;
  const int l15 = l & 15, l4 = l >> 4;
  const int wr = w >> 2, wc = w & 3;
  int bx = blockIdx.x, by = blockIdx.y;
  swz_block(bx, by);
  const int bm0 = by * 256, bn0 = bx * 256;
  const u16* Ab = A + (size_t)bm0 * K;
  const u16* Bb = Bw + (size_t)bn0 * K;

  f32x4 acc[8][4] = {};
  stage_op(Ab, K, 0, As[0], 0, 0, w, l);
  stage_op(Bb, K, 0, Bs[0], 0, 1, w, l);
  stage_op(Bb, K, 0, Bs[0], 1, 1, w, l);
  stage_op(Ab, K, 0, As[0], 1, 0, w, l);
  VMW4;                                    // hA0,hB0 resident; {hB1,hA1} in flight
  BAR;

  const int nk = K >> 6;
  int cur = 0;
  bf16x8 af[4][2], bfr[2][2];
  for (int kt = 0; kt < nk; ++kt) {
    const int kn = (kt + 1) << 6;
    const bool more = (kt + 1 < nk);
    u16* An = As[cur ^ 1];
    u16* Bn = Bs[cur ^ 1];
    // ---- phase A: quad(0,0); prefetch hA0(t+1) ----
    rdA(As[cur], wr, 0, l15, l4, af);
    rdB(Bs[cur], wc, 0, l15, l4, bfr);
    if (more) stage_op(Ab, K, kn, An, 0, 0, w, l);
    BAR;
    MFMA16(0, 0)
    if (more) { VMW4; } else { VMW2; }     // drain hB1(kt) for phase B
    BAR;
    // ---- phase B: quad(0,1); prefetch hB0(t+1) ----
    rdB(Bs[cur], wc, 1, l15, l4, bfr);
    if (more) stage_op(Bb, K, kn, Bn, 0, 1, w, l);
    BAR;
    MFMA16(0, 1)
    if (more) { VMW4; } else { VMW0; }     // drain hA1(kt) for phase C
    BAR;
    // ---- phase C: quad(1,1); prefetch hB1(t+1) ----
    rdA(As[cur], wr, 1, l15, l4, af);
    if (more) stage_op(Bb, K, kn, Bn, 1, 1, w, l);
    BAR;
    MFMA16(1, 1)
    BAR;
    // ---- phase D: quad(1,0); prefetch hA1(t+1) ----
    rdB(Bs[cur], wc, 0, l15, l4, bfr);
    if (more) stage_op(Ab, K, kn, An, 1, 0, w, l);
    BAR;
    MFMA16(1, 0)
    if (more) { VMW4; }                    // hA0,hB0(t+1) landed
    BAR;
    cur ^= 1;
  }

#pragma unroll
  for (int m = 0; m < 8; ++m) {
    const int row0 = bm0 + wr * 128 + m * 16 + l4 * 4;
#pragma unroll
    for (int n = 0; n < 4; ++n) {
      const int col = bn0 + wc * 64 + n * 16 + l15;
      // Q prescale folds 1/sqrt(64) AND log2(e) so attn softmax runs in exp2 domain
      const float qs = (col < qcols) ? 0.18033688f : 1.f;
#pragma unroll
      for (int r = 0; r < 4; ++r) {
        float v = acc[m][n][r] * qs;
        if constexpr (EPI == 1) v = v > 0.f ? v : 0.f;
        Cp[(size_t)(row0 + r) * N + col] = f2bf(v);
      }
    }
  }
}

// ====== 64x128 GEMM (2-buf, m97-style, 2 blocks/CU): C = res + A @ Bw^T (f32 out) ======
// 256 thr = 4 waves (2M x 2N, wave 32x64); grid (N/128, M/64) = 512 blocks.
__global__ __launch_bounds__(256, 2) void gemm64(const u16* __restrict__ A,
                                                 const u16* __restrict__ Bw,
                                                 float* __restrict__ C,
                                                 const float* __restrict__ res,
                                                 int M, int N, int K) {
  __shared__ __align__(16) u16 As[2][64 * 64];
  __shared__ __align__(16) u16 Bs[2][128 * 64];
  const int t = threadIdx.x, w = t >> 6, l = t & 63;
  const int l15 = l & 15, l4 = l >> 4;
  const int wr = w >> 1, wc = w & 1;              // 2M x 2N
  int bx = blockIdx.x, by = blockIdx.y;
  swz_block(bx, by);
  const int bm0 = by * 64, bn0 = bx * 128;
  const u16* Ab = A + (size_t)bm0 * K;
  const u16* Bb = Bw + (size_t)bn0 * K;

  auto stgA = [&](int buf, int kk) {
#pragma unroll
    for (int i = 0; i < 2; ++i) {                 // 512 slots (64 rows x 8 col8)
      const int s = t + i * 256;
      const int row = s >> 3;
      const int c8 = (l & 7) ^ (row & 7);
      GL_LDS16(Ab + (size_t)row * K + kk + c8 * 8, &As[buf][(s >> 6) * 512]);
    }
  };
  auto stgB = [&](int buf, int kk) {
#pragma unroll
    for (int i = 0; i < 4; ++i) {                 // 1024 slots (128 rows x 8 col8)
      const int s = t + i * 256;
      const int row = s >> 3;
      const int c8 = (l & 7) ^ (row & 7);
      GL_LDS16(Bb + (size_t)row * K + kk + c8 * 8, &Bs[buf][(s >> 6) * 512]);
    }
  };

  f32x4 acc[2][4] = {};
  stgA(0, 0); stgB(0, 0);
  const int nk = K >> 6;
  int cur = 0;
  for (int kt = 0; kt < nk; ++kt) {
    __syncthreads();                              // buf[cur] resident (vmcnt drained)
    if (kt + 1 < nk) { stgA(cur ^ 1, (kt + 1) << 6); stgB(cur ^ 1, (kt + 1) << 6); }
    bf16x8 af[2][2], bfr[4][2];
#pragma unroll
    for (int f = 0; f < 2; ++f) {
      const int row = wr * 32 + f * 16 + l15;
#pragma unroll
      for (int ks = 0; ks < 2; ++ks)
        af[f][ks] = ld8(&As[cur][row * 64 + (((ks * 4 + l4) ^ (row & 7)) * 8)]);
    }
#pragma unroll
    for (int n = 0; n < 4; ++n) {
      const int row = wc * 64 + n * 16 + l15;
#pragma unroll
      for (int ks = 0; ks < 2; ++ks)
        bfr[n][ks] = ld8(&Bs[cur][row * 64 + (((ks * 4 + l4) ^ (row & 7)) * 8)]);
    }
    __builtin_amdgcn_s_setprio(1);
#pragma unroll
    for (int f = 0; f < 2; ++f)
#pragma unroll
      for (int n = 0; n < 4; ++n) {
        acc[f][n] = __builtin_amdgcn_mfma_f32_16x16x32_bf16(af[f][0], bfr[n][0], acc[f][n], 0, 0, 0);
        acc[f][n] = __builtin_amdgcn_mfma_f32_16x16x32_bf16(af[f][1], bfr[n][1], acc[f][n], 0, 0, 0);
      }
    __builtin_amdgcn_s_setprio(0);
    __syncthreads();                              // reads of buf[cur] done
    cur ^= 1;
  }

#pragma unroll
  for (int f = 0; f < 2; ++f) {
    const int row0 = bm0 + wr * 32 + f * 16 + l4 * 4;
#pragma unroll
    for (int n = 0; n < 4; ++n) {
      const int col = bn0 + wc * 64 + n * 16 + l15;
#pragma unroll
      for (int r = 0; r < 4; ++r) {
        const size_t idx = (size_t)(row0 + r) * N + col;
        C[idx] = res[idx] + acc[f][n][r];
      }
    }
  }
}

// ---------------- causal flash attention v6: swapped QK^T, exp2-domain softmax ----------
// grid (16, B*H); paired q-tiles (p, 31-p). Q pre-scaled by log2(e)/sqrt(dk) in gemm8.
__global__ __launch_bounds__(256) void attn_k(const u16* __restrict__ Qm,
                                              const u16* __restrict__ Km,
                                              const u16* __restrict__ vt,
                                              u16* __restrict__ Om) {
  const int S = 2048, D = 1024, ldq = 3072;
  int p = blockIdx.x, bh = blockIdx.y;
  swz_block(p, bh);                          // same-bh pairs grouped per XCD
  const int bb = bh >> 4, h = bh & 15;
  const int t = threadIdx.x, w = t >> 6, l = t & 63, l15 = l & 15, l4 = l >> 4;
  const float NEGINF = -__builtin_inff();

  __shared__ __align__(16) u16 Ksm[2][64 * 64];
  __shared__ __align__(16) u16 Vsm[2][64 * 64];
  __shared__ __align__(16) u32 Psm[4][16 * 32];  // per-wave P, XOR-swizzled 16B blocks

  const u16* Qb = Qm + (size_t)bb * S * ldq + h * 64;
  const u16* Kb = Km + (size_t)bb * S * ldq + h * 64;
  const u16* Vtb = vt + (size_t)bh * 64 * 2048;

  auto stageKV = [&](int j, int buf) {
    const int k0 = j * 64;
#pragma unroll
    for (int i = 0; i < 2; ++i) {
      const int s = t + i * 256;
      const int row = s >> 3;
      const int colE = ((s & 7) ^ (row & 7)) * 8;
      GL_LDS16(Kb + (size_t)(k0 + row) * ldq + colE, &Ksm[buf][(s >> 6) * 512]);
      GL_LDS16(Vtb + (size_t)row * 2048 + k0 + colE, &Vsm[buf][(s >> 6) * 512]);
    }
  };

  u32* Pw = &Psm[w][0];
  const u16* Pu = (const u16*)Pw;
  const int h7 = l15 & 7;

  for (int half = 0; half < 2; ++half) {
    const int bx = half ? (31 - p) : p;
    const int q0 = bx * 64;
    __syncthreads();                         // prior half's LDS reads done
    stageKV(0, 0);

    bf16x8 qf[2];
    const int qq = q0 + w * 16 + l15;        // this lane's q-row
#pragma unroll
    for (int c = 0; c < 2; ++c) qf[c] = ld8(Qb + (size_t)qq * ldq + c * 32 + l4 * 8);

    f32x4 accT[4] = {};                      // O^T: dv = nf*16+l4*4+r, q = l15
    float mrow = NEGINF, lrow = 0.f;
    int cur = 0;

    for (int j = 0; j <= bx; ++j) {
      __syncthreads();                       // buf[cur] staged (vmcnt drained)
      if (j < bx) stageKV(j + 1, cur ^ 1);

      // S^T = K @ Q^T (log2 domain): sv[nf][r]: k-row, q-col=l15
      f32x4 sv[4] = {};
      __builtin_amdgcn_s_setprio(1);
#pragma unroll
      for (int c = 0; c < 2; ++c) {
#pragma unroll
        for (int nf = 0; nf < 4; ++nf) {
          const int row = nf * 16 + l15;
          bf16x8 kf = ld8(&Ksm[cur][row * 64 + ((c * 32 + l4 * 8) ^ ((row & 7) * 8))]);
          sv[nf] = __builtin_amdgcn_mfma_f32_16x16x32_bf16(kf, qf[c], sv[nf], 0, 0, 0);
        }
      }
      __builtin_amdgcn_s_setprio(0);

      if (j == bx) {                         // causal mask on diagonal tile
        const int k0 = j * 64;
#pragma unroll
        for (int nf = 0; nf < 4; ++nf) {
          const int kb = k0 + nf * 16 + l4 * 4;
#pragma unroll
          for (int r = 0; r < 4; ++r)
            if (kb + r > qq) sv[nf][r] = NEGINF;
        }
      }

      // row max: in-lane over 16, then xor16/xor32 (2 shuffles)
      f32x4 m4 = vmax4(vmax4(sv[0], sv[1]), vmax4(sv[2], sv[3]));
      float mt = fmaxf(fmaxf(m4[0], m4[1]), fmaxf(m4[2], m4[3]));
      mt = fmaxf(mt, __shfl_xor(mt, 16));
      mt = fmaxf(mt, __shfl_xor(mt, 32));
      const bool skip = __all(mt - mrow <= 11.54f);  // defer-max (=8 in e-domain)
      const float mnew = skip ? mrow : fmaxf(mrow, mt);
      if (!skip) {
        const float sf = exp2f(mrow - mnew);
        lrow *= sf;
#pragma unroll
        for (int nf = 0; nf < 4; ++nf) accT[nf] *= sf;  // q=l15: lane-local!
        mrow = mnew;
      }
#pragma unroll
      for (int nf = 0; nf < 4; ++nf)
#pragma unroll
        for (int r = 0; r < 4; ++r) sv[nf][r] = exp2f(sv[nf][r] - mnew);
      f32x4 s4 = (sv[0] + sv[1]) + (sv[2] + sv[3]);
      float ps = (s4[0] + s4[1]) + (s4[2] + s4[3]);
      ps += __shfl_xor(ps, 16);
      ps += __shfl_xor(ps, 32);
      lrow += ps;

      // pack P -> bf16 pairs -> per-wave LDS (XOR-swizzled 16B blocks)
#pragma unroll
      for (int nf = 0; nf < 4; ++nf) {
        u32 lo, hi;
        asm("v_cvt_pk_bf16_f32 %0, %1, %2" : "=v"(lo) : "v"(sv[nf][0]), "v"(sv[nf][1]));
        asm("v_cvt_pk_bf16_f32 %0, %1, %2" : "=v"(hi) : "v"(sv[nf][2]), "v"(sv[nf][3]));
        const int kw4 = (nf * 2 + (l4 >> 1)) ^ h7;
        const int base = l15 * 32 + kw4 * 4 + (l4 & 1) * 2;
        Pw[base] = lo;
        Pw[base + 1] = hi;
      }

      // O^T += V^T-frag @ P : accT[nf] q=l15, dv=nf*16+l4*4+r
      __builtin_amdgcn_s_setprio(1);
#pragma unroll
      for (int c = 0; c < 2; ++c) {
        bf16x8 pf = ld8(Pu + l15 * 64 + ((c * 4 + l4) ^ h7) * 8);
#pragma unroll
        for (int nf = 0; nf < 4; ++nf) {
          const int row = nf * 16 + l15;
          bf16x8 vf = ld8(&Vsm[cur][row * 64 + ((c * 32 + l4 * 8) ^ ((row & 7) * 8))]);
          accT[nf] = __builtin_amdgcn_mfma_f32_16x16x32_bf16(vf, pf, accT[nf], 0, 0, 0);
        }
      }
      __builtin_amdgcn_s_setprio(0);
      cur ^= 1;
    }

    // epilogue: lane-local divide; 8B packed stores
    const float inv = 1.f / lrow;
    u16* orow = Om + ((size_t)bb * S + qq) * D + h * 64;
#pragma unroll
    for (int nf = 0; nf < 4; ++nf) {
      u16x4 ov;
#pragma unroll
      for (int r = 0; r < 4; ++r) ov[r] = f2bf(accT[nf][r] * inv);
      *(u16x4_a*)(orow + nf * 16 + l4 * 4) = ov;
    }
  }
}

// ---------------- orchestration ----------------
extern "C" void kernel_launch(void* const* d_in, const int* in_sizes, int n_in,
                              void* d_out, int out_size, void* d_ws, size_t ws_size,
                              hipStream_t stream) {
  (void)in_sizes; (void)n_in; (void)out_size; (void)ws_size;
  const float* x    = (const float*)d_in[0];
  const float* W_q  = (const float*)d_in[1];
  const float* W_k  = (const float*)d_in[2];
  const float* W_v  = (const float*)d_in[3];
  const float* W_o  = (const float*)d_in[4];
  const float* W1   = (const float*)d_in[5];
  const float* W2   = (const float*)d_in[6];
  const float* ln1w = (const float*)d_in[7];
  const float* ln1b = (const float*)d_in[8];
  const float* ln2w = (const float*)d_in[9];
  const float* ln2b = (const float*)d_in[10];

  const size_t MB = 1ull << 20;
  char* W = (char*)d_ws;
  u16* wqkv  = (u16*)(W + 0);        //  6 MB  packed [3072][1024] bf16
  u16* wo    = (u16*)(W + 6 * MB);   //  2 MB
  u16* w1b   = (u16*)(W + 8 * MB);   //  8 MB
  u16* w2b   = (u16*)(W + 16 * MB);  //  8 MB
  u16* xn1   = (u16*)(W + 24 * MB);  //  8 MB
  u16* qkv   = (u16*)(W + 32 * MB);  // 24 MB  [4096][3072] bf16 (Q pre-scaled)
  u16* attnb = (u16*)(W + 56 * MB);  //  8 MB
  u16* vt    = (u16*)(W + 64 * MB);  //  8 MB  V^T; dead after attn
  u16* xn2   = (u16*)(W + 64 * MB);  //  8 MB  (shares with vt)
  u16* hbuf  = (u16*)(W + 24 * MB);  // 32 MB, reuses dead xn1+qkv region
  float* x2  = (float*)d_out;        // residual stream lives in d_out

  // all six weight converts in one launch
  Cvt6 c;
  c.s[0] = W_q; c.d[0] = wqkv;              c.n4[0] = 1 << 18;
  c.s[1] = W_k; c.d[1] = wqkv + (1 << 20);  c.n4[1] = 1 << 18;
  c.s[2] = W_v; c.d[2] = wqkv + (2 << 20);  c.n4[2] = 1 << 18;
  c.s[3] = W_o; c.d[3] = wo;                c.n4[3] = 1 << 18;
  c.s[4] = W1;  c.d[4] = w1b;               c.n4[4] = 1 << 20;
  c.s[5] = W2;  c.d[5] = w2b;               c.n4[5] = 1 << 20;
  cvt6_k<<<dim3(4096, 6), dim3(256), 0, stream>>>(c);

  ln_k<<<dim3(4096), dim3(256), 0, stream>>>(x, ln1w, ln1b, xn1);
  // fused QKV projection (8-phase 256²; Q cols pre-scaled by log2e/8)
  gemm8<0><<<dim3(12, 16), dim3(512), 0, stream>>>(xn1, wqkv, qkv, 4096, 3072, 1024, 1024);
  vtr_k<<<dim3(32, 32), dim3(256), 0, stream>>>(qkv + 2048, vt);
  attn_k<<<dim3(16, 32), dim3(256), 0, stream>>>(qkv, qkv + 1024, vt, attnb);
  // x2 = x + attn @ Wo^T   (64x128 2-block/CU, residual fused)
  gemm64<<<dim3(8, 64), dim3(256), 0, stream>>>(attnb, wo, x2, x, 4096, 1024, 1024);
  ln_k<<<dim3(4096), dim3(256), 0, stream>>>(x2, ln2w, ln2b, xn2);
  // h = relu(xn2 @ W1^T)  (8-phase 256²)
  gemm8<1><<<dim3(16, 16), dim3(512), 0, stream>>>(xn2, w1b, hbuf, 4096, 4096, 1024, 0);
  // out = x2 + h @ W2^T  (64x128 2-block/CU, in-place residual on d_out)
  gemm64<<<dim3(8, 64), dim3(256), 0, stream>>>(hbuf, w2b, x2, x2, 4096, 1024, 4096);
}

// Round 15
// 224.083 us; speedup vs baseline: 1.1855x; 1.0325x over previous
//
#include <hip/hip_runtime.h>
#include <stdint.h>

typedef unsigned short u16;
typedef unsigned int u32;
typedef __bf16 bf16x8 __attribute__((ext_vector_type(8)));
typedef float f32x4 __attribute__((ext_vector_type(4)));
typedef unsigned short u16x8 __attribute__((ext_vector_type(8)));
typedef unsigned short u16x4 __attribute__((ext_vector_type(4)));
typedef u16x8 u16x8_a __attribute__((may_alias));
typedef u16x4 u16x4_a __attribute__((may_alias));

#define DEV static __device__ __forceinline__

DEV u16 f2bf(float f) {
  unsigned u = __builtin_bit_cast(unsigned, f);
  u += 0x7fffu + ((u >> 16) & 1u);   // RNE
  return (u16)(u >> 16);
}
DEV bf16x8 ld8(const u16* p) {
  u16x8 v = *(const u16x8_a*)p;
  return __builtin_bit_cast(bf16x8, v);
}
DEV f32x4 vmax4(f32x4 a, f32x4 b) {
  f32x4 r;
  r[0] = fmaxf(a[0], b[0]); r[1] = fmaxf(a[1], b[1]);
  r[2] = fmaxf(a[2], b[2]); r[3] = fmaxf(a[3], b[3]);
  return r;
}
// bijective XCD swizzle (m204)
DEV void swz_block(int& bx, int& by) {
  const int gx = gridDim.x;
  const int nwg = gx * gridDim.y;
  int lin = by * gx + bx;
  const int q = nwg >> 3, r = nwg & 7, x = lin & 7, p = lin >> 3;
  lin = (x < r ? x * (q + 1) : r * (q + 1) + (x - r) * q) + p;
  bx = lin % gx; by = lin / gx;
}

#define GL_LDS16(gp, lp)                                                        \
  __builtin_amdgcn_global_load_lds(                                             \
      (const __attribute__((address_space(1))) void*)(gp),                      \
      (__attribute__((address_space(3))) void*)(lp), 16, 0, 0)

#define VMW4 asm volatile("s_waitcnt vmcnt(4)" ::: "memory")
#define VMW2 asm volatile("s_waitcnt vmcnt(2)" ::: "memory")
#define VMW0 asm volatile("s_waitcnt vmcnt(0)" ::: "memory")
#define BAR  __builtin_amdgcn_s_barrier()

// ---------------- fused f32 -> bf16 convert for all 6 weights (one launch) ----------------
struct Cvt6 {
  const float* s[6];
  u16* d[6];
  int n4[6];
};
__global__ __launch_bounds__(256) void cvt6_k(Cvt6 c) {
  const int yi = blockIdx.y;
  const int i = blockIdx.x * 256 + threadIdx.x;
  if (i < c.n4[yi]) {
    float4 v = ((const float4*)c.s[yi])[i];
    u16x4 o;
    o[0] = f2bf(v.x); o[1] = f2bf(v.y); o[2] = f2bf(v.z); o[3] = f2bf(v.w);
    *(u16x4_a*)(c.d[yi] + (size_t)i * 4) = o;
  }
}

// ---------------- layernorm (f32 in, bf16 out) ----------------
__global__ __launch_bounds__(256) void ln_k(const float* __restrict__ x,
                                            const float* __restrict__ w,
                                            const float* __restrict__ b,
                                            u16* __restrict__ o) {
  const int row = blockIdx.x, t = threadIdx.x;
  const float4 v = ((const float4*)(x + (size_t)row * 1024))[t];
  float s = v.x + v.y + v.z + v.w;
  float q = v.x * v.x + v.y * v.y + v.z * v.z + v.w * v.w;
#pragma unroll
  for (int m = 1; m < 64; m <<= 1) { s += __shfl_xor(s, m); q += __shfl_xor(q, m); }
  __shared__ float ss[4], qq[4];
  if ((t & 63) == 0) { ss[t >> 6] = s; qq[t >> 6] = q; }
  __syncthreads();
  s = ss[0] + ss[1] + ss[2] + ss[3];
  q = qq[0] + qq[1] + qq[2] + qq[3];
  const float mean = s * (1.f / 1024.f);
  const float var = q * (1.f / 1024.f) - mean * mean;
  const float rstd = rsqrtf(var + 1e-5f);
  const float4 wv = ((const float4*)w)[t];
  const float4 bv = ((const float4*)b)[t];
  u16x4 ov;
  ov[0] = f2bf((v.x - mean) * rstd * wv.x + bv.x);
  ov[1] = f2bf((v.y - mean) * rstd * wv.y + bv.y);
  ov[2] = f2bf((v.z - mean) * rstd * wv.z + bv.z);
  ov[3] = f2bf((v.w - mean) * rstd * wv.w + bv.w);
  *(u16x4_a*)(o + (size_t)row * 1024 + t * 4) = ov;
}

// ---------------- V transpose ----------------
__global__ __launch_bounds__(256) void vtr_k(const u16* __restrict__ qkvV,
                                             u16* __restrict__ vt) {
  __shared__ u16 T[64][65];
  const int st = blockIdx.x, bh = blockIdx.y;
  const int b = bh >> 4, h = bh & 15;
  const int t = threadIdx.x;
  const u16* src = qkvV + ((size_t)(b * 2048 + st * 64)) * 3072 + h * 64;
  const int r = t >> 2, c0 = (t & 3) * 16;
  u16x8 a0 = *(const u16x8_a*)(src + (size_t)r * 3072 + c0);
  u16x8 a1 = *(const u16x8_a*)(src + (size_t)r * 3072 + c0 + 8);
#pragma unroll
  for (int e = 0; e < 8; ++e) { T[r][c0 + e] = a0[e]; T[r][c0 + 8 + e] = a1[e]; }
  __syncthreads();
  const int d = t >> 2, s0 = (t & 3) * 16;
  u16x8 o0, o1;
#pragma unroll
  for (int e = 0; e < 8; ++e) { o0[e] = T[s0 + e][d]; o1[e] = T[s0 + 8 + e][d]; }
  u16* dst = vt + ((size_t)bh * 64 + d) * 2048 + (size_t)st * 64 + s0;
  *(u16x8_a*)dst = o0;
  *(u16x8_a*)(dst + 8) = o1;
}

// ================= 256x256 8-phase GEMM, rolling counted-vmcnt schedule =================
DEV void stage_op(const u16* __restrict__ G, int K, int kk, u16* lds, int set,
                  int isB, int w, int l) {
#pragma unroll
  for (int i = 0; i < 2; ++i) {
    const int c = i * 8 + w;                 // chunk 0..15 (1KB, 8 rows)
    int rb;
    if (!isB) { const int lr = c * 8; rb = (lr < 64 ? lr : lr + 64) + set * 64; }
    else      { rb = (c >> 2) * 64 + set * 32 + (c & 3) * 8; }
    const int row = rb + (l >> 3);
    const int c8 = (l & 7) ^ (row & 7);      // inverse-swizzled source col
    GL_LDS16(G + (size_t)row * K + kk + c8 * 8, lds + rb * 64);
  }
}
DEV void rdA(const u16* as, int wr, int mh, int l15, int l4, bf16x8 af[4][2]) {
#pragma unroll
  for (int f = 0; f < 4; ++f) {
    const int row = wr * 128 + mh * 64 + f * 16 + l15;
#pragma unroll
    for (int ks = 0; ks < 2; ++ks) {
      const int c8 = (ks * 4 + l4) ^ (row & 7);
      af[f][ks] = ld8(as + row * 64 + c8 * 8);
    }
  }
}
DEV void rdB(const u16* bs, int wc, int nh, int l15, int l4, bf16x8 bf_[2][2]) {
#pragma unroll
  for (int g = 0; g < 2; ++g) {
    const int row = wc * 64 + nh * 32 + g * 16 + l15;
#pragma unroll
    for (int ks = 0; ks < 2; ++ks) {
      const int c8 = (ks * 4 + l4) ^ (row & 7);
      bf_[g][ks] = ld8(bs + row * 64 + c8 * 8);
    }
  }
}

#define MFMA16(mh, nh)                                                          \
  __builtin_amdgcn_s_setprio(1);                                                \
  _Pragma("unroll")                                                             \
  for (int f = 0; f < 4; ++f) {                                                 \
    _Pragma("unroll")                                                           \
    for (int g = 0; g < 2; ++g) {                                               \
      f32x4& a_ = acc[(mh) * 4 + f][(nh) * 2 + g];                              \
      a_ = __builtin_amdgcn_mfma_f32_16x16x32_bf16(af[f][0], bfr[g][0], a_, 0, 0, 0); \
      a_ = __builtin_amdgcn_mfma_f32_16x16x32_bf16(af[f][1], bfr[g][1], a_, 0, 0, 0); \
    }                                                                           \
  }                                                                             \
  __builtin_amdgcn_s_setprio(0);

template <int EPI>
__global__ __launch_bounds__(512, 2) void gemm8(const u16* __restrict__ A,
                                                const u16* __restrict__ Bw,
                                                u16* __restrict__ Cp,
                                                int M, int N, int K, int qcols) {
  __shared__ __align__(16) u16 As[2][256 * 64];
  __shared__ __align__(16) u16 Bs[2][256 * 64];
  const int t = threadIdx.x, w = t >> 6, l = t & 63;
  const int l15 = l & 15, l4 = l >> 4;
  const int wr = w >> 2, wc = w & 3;
  int bx = blockIdx.x, by = blockIdx.y;
  swz_block(bx, by);
  const int bm0 = by * 256, bn0 = bx * 256;
  const u16* Ab = A + (size_t)bm0 * K;
  const u16* Bb = Bw + (size_t)bn0 * K;

  f32x4 acc[8][4] = {};
  stage_op(Ab, K, 0, As[0], 0, 0, w, l);
  stage_op(Bb, K, 0, Bs[0], 0, 1, w, l);
  stage_op(Bb, K, 0, Bs[0], 1, 1, w, l);
  stage_op(Ab, K, 0, As[0], 1, 0, w, l);
  VMW4;                                    // hA0,hB0 resident; {hB1,hA1} in flight
  BAR;

  const int nk = K >> 6;
  int cur = 0;
  bf16x8 af[4][2], bfr[2][2];
  for (int kt = 0; kt < nk; ++kt) {
    const int kn = (kt + 1) << 6;
    const bool more = (kt + 1 < nk);
    u16* An = As[cur ^ 1];
    u16* Bn = Bs[cur ^ 1];
    // ---- phase A: quad(0,0); prefetch hA0(t+1) ----
    rdA(As[cur], wr, 0, l15, l4, af);
    rdB(Bs[cur], wc, 0, l15, l4, bfr);
    if (more) stage_op(Ab, K, kn, An, 0, 0, w, l);
    BAR;
    MFMA16(0, 0)
    if (more) { VMW4; } else { VMW2; }     // drain hB1(kt) for phase B
    BAR;
    // ---- phase B: quad(0,1); prefetch hB0(t+1) ----
    rdB(Bs[cur], wc, 1, l15, l4, bfr);
    if (more) stage_op(Bb, K, kn, Bn, 0, 1, w, l);
    BAR;
    MFMA16(0, 1)
    if (more) { VMW4; } else { VMW0; }     // drain hA1(kt) for phase C
    BAR;
    // ---- phase C: quad(1,1); prefetch hB1(t+1) ----
    rdA(As[cur], wr, 1, l15, l4, af);
    if (more) stage_op(Bb, K, kn, Bn, 1, 1, w, l);
    BAR;
    MFMA16(1, 1)
    BAR;
    // ---- phase D: quad(1,0); prefetch hA1(t+1) ----
    rdB(Bs[cur], wc, 0, l15, l4, bfr);
    if (more) stage_op(Ab, K, kn, An, 1, 0, w, l);
    BAR;
    MFMA16(1, 0)
    if (more) { VMW4; }                    // hA0,hB0(t+1) landed
    BAR;
    cur ^= 1;
  }

#pragma unroll
  for (int m = 0; m < 8; ++m) {
    const int row0 = bm0 + wr * 128 + m * 16 + l4 * 4;
#pragma unroll
    for (int n = 0; n < 4; ++n) {
      const int col = bn0 + wc * 64 + n * 16 + l15;
      // Q prescale folds 1/sqrt(64) AND log2(e) so attn softmax runs in exp2 domain
      const float qs = (col < qcols) ? 0.18033688f : 1.f;
#pragma unroll
      for (int r = 0; r < 4; ++r) {
        float v = acc[m][n][r] * qs;
        if constexpr (EPI == 1) v = v > 0.f ? v : 0.f;
        Cp[(size_t)(row0 + r) * N + col] = f2bf(v);
      }
    }
  }
}

// ====== 64x128 GEMM (2-buf, m97-style, 2 blocks/CU): C = res + A @ Bw^T (f32 out) ======
// 256 thr = 4 waves (2M x 2N, wave 32x64); grid (N/128, M/64) = 512 blocks.
__global__ __launch_bounds__(256, 2) void gemm64(const u16* __restrict__ A,
                                                 const u16* __restrict__ Bw,
                                                 float* __restrict__ C,
                                                 const float* __restrict__ res,
                                                 int M, int N, int K) {
  __shared__ __align__(16) u16 As[2][64 * 64];
  __shared__ __align__(16) u16 Bs[2][128 * 64];
  const int t = threadIdx.x, w = t >> 6, l = t & 63;
  const int l15 = l & 15, l4 = l >> 4;
  const int wr = w >> 1, wc = w & 1;              // 2M x 2N
  int bx = blockIdx.x, by = blockIdx.y;
  swz_block(bx, by);
  const int bm0 = by * 64, bn0 = bx * 128;
  const u16* Ab = A + (size_t)bm0 * K;
  const u16* Bb = Bw + (size_t)bn0 * K;

  auto stgA = [&](int buf, int kk) {
#pragma unroll
    for (int i = 0; i < 2; ++i) {                 // 512 slots (64 rows x 8 col8)
      const int s = t + i * 256;
      const int row = s >> 3;
      const int c8 = (l & 7) ^ (row & 7);
      GL_LDS16(Ab + (size_t)row * K + kk + c8 * 8, &As[buf][(s >> 6) * 512]);
    }
  };
  auto stgB = [&](int buf, int kk) {
#pragma unroll
    for (int i = 0; i < 4; ++i) {                 // 1024 slots (128 rows x 8 col8)
      const int s = t + i * 256;
      const int row = s >> 3;
      const int c8 = (l & 7) ^ (row & 7);
      GL_LDS16(Bb + (size_t)row * K + kk + c8 * 8, &Bs[buf][(s >> 6) * 512]);
    }
  };

  f32x4 acc[2][4] = {};
  stgA(0, 0); stgB(0, 0);
  const int nk = K >> 6;
  int cur = 0;
  for (int kt = 0; kt < nk; ++kt) {
    __syncthreads();                              // buf[cur] resident (vmcnt drained)
    if (kt + 1 < nk) { stgA(cur ^ 1, (kt + 1) << 6); stgB(cur ^ 1, (kt + 1) << 6); }
    bf16x8 af[2][2], bfr[4][2];
#pragma unroll
    for (int f = 0; f < 2; ++f) {
      const int row = wr * 32 + f * 16 + l15;
#pragma unroll
      for (int ks = 0; ks < 2; ++ks)
        af[f][ks] = ld8(&As[cur][row * 64 + (((ks * 4 + l4) ^ (row & 7)) * 8)]);
    }
#pragma unroll
    for (int n = 0; n < 4; ++n) {
      const int row = wc * 64 + n * 16 + l15;
#pragma unroll
      for (int ks = 0; ks < 2; ++ks)
        bfr[n][ks] = ld8(&Bs[cur][row * 64 + (((ks * 4 + l4) ^ (row & 7)) * 8)]);
    }
    __builtin_amdgcn_s_setprio(1);
#pragma unroll
    for (int f = 0; f < 2; ++f)
#pragma unroll
      for (int n = 0; n < 4; ++n) {
        acc[f][n] = __builtin_amdgcn_mfma_f32_16x16x32_bf16(af[f][0], bfr[n][0], acc[f][n], 0, 0, 0);
        acc[f][n] = __builtin_amdgcn_mfma_f32_16x16x32_bf16(af[f][1], bfr[n][1], acc[f][n], 0, 0, 0);
      }
    __builtin_amdgcn_s_setprio(0);
    __syncthreads();                              // reads of buf[cur] done
    cur ^= 1;
  }

#pragma unroll
  for (int f = 0; f < 2; ++f) {
    const int row0 = bm0 + wr * 32 + f * 16 + l4 * 4;
#pragma unroll
    for (int n = 0; n < 4; ++n) {
      const int col = bn0 + wc * 64 + n * 16 + l15;
#pragma unroll
      for (int r = 0; r < 4; ++r) {
        const size_t idx = (size_t)(row0 + r) * N + col;
        C[idx] = res[idx] + acc[f][n][r];
      }
    }
  }
}

// ---------------- causal flash attention v7: native exp2 softmax ----------
// grid (16, B*H); paired q-tiles (p, 31-p). Q pre-scaled by log2(e)/sqrt(dk) in gemm8.
__global__ __launch_bounds__(256) void attn_k(const u16* __restrict__ Qm,
                                              const u16* __restrict__ Km,
                                              const u16* __restrict__ vt,
                                              u16* __restrict__ Om) {
  const int S = 2048, D = 1024, ldq = 3072;
  int p = blockIdx.x, bh = blockIdx.y;
  swz_block(p, bh);                          // same-bh pairs grouped per XCD
  const int bb = bh >> 4, h = bh & 15;
  const int t = threadIdx.x, w = t >> 6, l = t & 63, l15 = l & 15, l4 = l >> 4;
  const float NEGINF = -__builtin_inff();

  __shared__ __align__(16) u16 Ksm[2][64 * 64];
  __shared__ __align__(16) u16 Vsm[2][64 * 64];
  __shared__ __align__(16) u32 Psm[4][16 * 32];  // per-wave P, XOR-swizzled 16B blocks

  const u16* Qb = Qm + (size_t)bb * S * ldq + h * 64;
  const u16* Kb = Km + (size_t)bb * S * ldq + h * 64;
  const u16* Vtb = vt + (size_t)bh * 64 * 2048;

  auto stageKV = [&](int j, int buf) {
    const int k0 = j * 64;
#pragma unroll
    for (int i = 0; i < 2; ++i) {
      const int s = t + i * 256;
      const int row = s >> 3;
      const int colE = ((s & 7) ^ (row & 7)) * 8;
      GL_LDS16(Kb + (size_t)(k0 + row) * ldq + colE, &Ksm[buf][(s >> 6) * 512]);
      GL_LDS16(Vtb + (size_t)row * 2048 + k0 + colE, &Vsm[buf][(s >> 6) * 512]);
    }
  };

  u32* Pw = &Psm[w][0];
  const u16* Pu = (const u16*)Pw;
  const int h7 = l15 & 7;

  for (int half = 0; half < 2; ++half) {
    const int bx = half ? (31 - p) : p;
    const int q0 = bx * 64;
    __syncthreads();                         // prior half's LDS reads done
    stageKV(0, 0);

    bf16x8 qf[2];
    const int qq = q0 + w * 16 + l15;        // this lane's q-row
#pragma unroll
    for (int c = 0; c < 2; ++c) qf[c] = ld8(Qb + (size_t)qq * ldq + c * 32 + l4 * 8);

    f32x4 accT[4] = {};                      // O^T: dv = nf*16+l4*4+r, q = l15
    float mrow = NEGINF, lrow = 0.f;
    int cur = 0;

    for (int j = 0; j <= bx; ++j) {
      __syncthreads();                       // buf[cur] staged (vmcnt drained)
      if (j < bx) stageKV(j + 1, cur ^ 1);

      // S^T = K @ Q^T (log2 domain): sv[nf][r]: k-row, q-col=l15
      f32x4 sv[4] = {};
      __builtin_amdgcn_s_setprio(1);
#pragma unroll
      for (int c = 0; c < 2; ++c) {
#pragma unroll
        for (int nf = 0; nf < 4; ++nf) {
          const int row = nf * 16 + l15;
          bf16x8 kf = ld8(&Ksm[cur][row * 64 + ((c * 32 + l4 * 8) ^ ((row & 7) * 8))]);
          sv[nf] = __builtin_amdgcn_mfma_f32_16x16x32_bf16(kf, qf[c], sv[nf], 0, 0, 0);
        }
      }
      __builtin_amdgcn_s_setprio(0);

      if (j == bx) {                         // causal mask on diagonal tile
        const int k0 = j * 64;
#pragma unroll
        for (int nf = 0; nf < 4; ++nf) {
          const int kb = k0 + nf * 16 + l4 * 4;
#pragma unroll
          for (int r = 0; r < 4; ++r)
            if (kb + r > qq) sv[nf][r] = NEGINF;
        }
      }

      // row max: in-lane over 16, then xor16/xor32 (2 shuffles)
      f32x4 m4 = vmax4(vmax4(sv[0], sv[1]), vmax4(sv[2], sv[3]));
      float mt = fmaxf(fmaxf(m4[0], m4[1]), fmaxf(m4[2], m4[3]));
      mt = fmaxf(mt, __shfl_xor(mt, 16));
      mt = fmaxf(mt, __shfl_xor(mt, 32));
      const bool skip = __all(mt - mrow <= 11.54f);  // defer-max (=8 in e-domain)
      const float mnew = skip ? mrow : fmaxf(mrow, mt);
      if (!skip) {
        const float sf = __builtin_amdgcn_exp2f(mrow - mnew);   // native v_exp_f32
        lrow *= sf;
#pragma unroll
        for (int nf = 0; nf < 4; ++nf) accT[nf] *= sf;  // q=l15: lane-local!
        mrow = mnew;
      }
#pragma unroll
      for (int nf = 0; nf < 4; ++nf)
#pragma unroll
        for (int r = 0; r < 4; ++r)
          sv[nf][r] = __builtin_amdgcn_exp2f(sv[nf][r] - mnew); // native v_exp_f32
      f32x4 s4 = (sv[0] + sv[1]) + (sv[2] + sv[3]);
      float ps = (s4[0] + s4[1]) + (s4[2] + s4[3]);
      ps += __shfl_xor(ps, 16);
      ps += __shfl_xor(ps, 32);
      lrow += ps;

      // pack P -> bf16 pairs -> per-wave LDS (XOR-swizzled 16B blocks)
#pragma unroll
      for (int nf = 0; nf < 4; ++nf) {
        u32 lo, hi;
        asm("v_cvt_pk_bf16_f32 %0, %1, %2" : "=v"(lo) : "v"(sv[nf][0]), "v"(sv[nf][1]));
        asm("v_cvt_pk_bf16_f32 %0, %1, %2" : "=v"(hi) : "v"(sv[nf][2]), "v"(sv[nf][3]));
        const int kw4 = (nf * 2 + (l4 >> 1)) ^ h7;
        const int base = l15 * 32 + kw4 * 4 + (l4 & 1) * 2;
        Pw[base] = lo;
        Pw[base + 1] = hi;
      }

      // O^T += V^T-frag @ P : accT[nf] q=l15, dv=nf*16+l4*4+r
      __builtin_amdgcn_s_setprio(1);
#pragma unroll
      for (int c = 0; c < 2; ++c) {
        bf16x8 pf = ld8(Pu + l15 * 64 + ((c * 4 + l4) ^ h7) * 8);
#pragma unroll
        for (int nf = 0; nf < 4; ++nf) {
          const int row = nf * 16 + l15;
          bf16x8 vf = ld8(&Vsm[cur][row * 64 + ((c * 32 + l4 * 8) ^ ((row & 7) * 8))]);
          accT[nf] = __builtin_amdgcn_mfma_f32_16x16x32_bf16(vf, pf, accT[nf], 0, 0, 0);
        }
      }
      __builtin_amdgcn_s_setprio(0);
      cur ^= 1;
    }

    // epilogue: lane-local divide; 8B packed stores
    const float inv = 1.f / lrow;
    u16* orow = Om + ((size_t)bb * S + qq) * D + h * 64;
#pragma unroll
    for (int nf = 0; nf < 4; ++nf) {
      u16x4 ov;
#pragma unroll
      for (int r = 0; r < 4; ++r) ov[r] = f2bf(accT[nf][r] * inv);
      *(u16x4_a*)(orow + nf * 16 + l4 * 4) = ov;
    }
  }
}

// ---------------- orchestration ----------------
extern "C" void kernel_launch(void* const* d_in, const int* in_sizes, int n_in,
                              void* d_out, int out_size, void* d_ws, size_t ws_size,
                              hipStream_t stream) {
  (void)in_sizes; (void)n_in; (void)out_size; (void)ws_size;
  const float* x    = (const float*)d_in[0];
  const float* W_q  = (const float*)d_in[1];
  const float* W_k  = (const float*)d_in[2];
  const float* W_v  = (const float*)d_in[3];
  const float* W_o  = (const float*)d_in[4];
  const float* W1   = (const float*)d_in[5];
  const float* W2   = (const float*)d_in[6];
  const float* ln1w = (const float*)d_in[7];
  const float* ln1b = (const float*)d_in[8];
  const float* ln2w = (const float*)d_in[9];
  const float* ln2b = (const float*)d_in[10];

  const size_t MB = 1ull << 20;
  char* W = (char*)d_ws;
  u16* wqkv  = (u16*)(W + 0);        //  6 MB  packed [3072][1024] bf16
  u16* wo    = (u16*)(W + 6 * MB);   //  2 MB
  u16* w1b   = (u16*)(W + 8 * MB);   //  8 MB
  u16* w2b   = (u16*)(W + 16 * MB);  //  8 MB
  u16* xn1   = (u16*)(W + 24 * MB);  //  8 MB
  u16* qkv   = (u16*)(W + 32 * MB);  // 24 MB  [4096][3072] bf16 (Q pre-scaled)
  u16* attnb = (u16*)(W + 56 * MB);  //  8 MB
  u16* vt    = (u16*)(W + 64 * MB);  //  8 MB  V^T; dead after attn
  u16* xn2   = (u16*)(W + 64 * MB);  //  8 MB  (shares with vt)
  u16* hbuf  = (u16*)(W + 24 * MB);  // 32 MB, reuses dead xn1+qkv region
  float* x2  = (float*)d_out;        // residual stream lives in d_out

  // all six weight converts in one launch
  Cvt6 c;
  c.s[0] = W_q; c.d[0] = wqkv;              c.n4[0] = 1 << 18;
  c.s[1] = W_k; c.d[1] = wqkv + (1 << 20);  c.n4[1] = 1 << 18;
  c.s[2] = W_v; c.d[2] = wqkv + (2 << 20);  c.n4[2] = 1 << 18;
  c.s[3] = W_o; c.d[3] = wo;                c.n4[3] = 1 << 18;
  c.s[4] = W1;  c.d[4] = w1b;               c.n4[4] = 1 << 20;
  c.s[5] = W2;  c.d[5] = w2b;               c.n4[5] = 1 << 20;
  cvt6_k<<<dim3(4096, 6), dim3(256), 0, stream>>>(c);

  ln_k<<<dim3(4096), dim3(256), 0, stream>>>(x, ln1w, ln1b, xn1);
  // fused QKV projection (8-phase 256²; Q cols pre-scaled by log2e/8)
  gemm8<0><<<dim3(12, 16), dim3(512), 0, stream>>>(xn1, wqkv, qkv, 4096, 3072, 1024, 1024);
  vtr_k<<<dim3(32, 32), dim3(256), 0, stream>>>(qkv + 2048, vt);
  attn_k<<<dim3(16, 32), dim3(256), 0, stream>>>(qkv, qkv + 1024, vt, attnb);
  // x2 = x + attn @ Wo^T   (64x128 2-block/CU, residual fused)
  gemm64<<<dim3(8, 64), dim3(256), 0, stream>>>(attnb, wo, x2, x, 4096, 1024, 1024);
  ln_k<<<dim3(4096), dim3(256), 0, stream>>>(x2, ln2w, ln2b, xn2);
  // h = relu(xn2 @ W1^T)  (8-phase 256²)
  gemm8<1><<<dim3(16, 16), dim3(512), 0, stream>>>(xn2, w1b, hbuf, 4096, 4096, 1024, 0);
  // out = x2 + h @ W2^T  (64x128 2-block/CU, in-place residual on d_out)
  gemm64<<<dim3(8, 64), dim3(256), 0, stream>>>(hbuf, w2b, x2, x2, 4096, 1024, 4096);
}